// Round 8
// baseline (4176.941 us; speedup 1.0000x reference)
//
#include <hip/hip_runtime.h>
#include <hip/hip_bf16.h>

// GPT-2 small forward on gfx950. bf16 MFMA GEMMs (f32 accum), flash attention.
// R8: gemm256 -> true m201-style schedule: per-phase {ds_read -> barrier ->
//     lgkmcnt(0) -> setprio(1) 16xMFMA setprio(0) -> barrier}; full-tile-ahead
//     prefetch (all 8 loads of T+2 issued at T's boundary) with counted
//     vmcnt(8) -- loads get a full K-tile (~700cy) in flight before the wait.
//     R7's boundary waited on loads issued ~150cy earlier -> 500-600cy stall
//     per tile = the measured 26% MfmaUtil.

typedef __bf16 bh_t;
typedef __bf16 bfx4 __attribute__((ext_vector_type(4)));
typedef __bf16 bfx8 __attribute__((ext_vector_type(8)));
typedef float  fx4  __attribute__((ext_vector_type(4)));

#define CDIM 768
#define TSEQ 1024
#define NHEAD 12
#define HDIM 64
#define NLAYER 12
#define MROWS 4096          // B*T
#define VOCAB 50257
#define VPAD  50432         // 197 * 256

__device__ __forceinline__ void gload_lds16(const void* g, void* l) {
  __builtin_amdgcn_global_load_lds(
      (const __attribute__((address_space(1))) void*)g,
      (__attribute__((address_space(3))) void*)l, 16, 0, 0);
}

__device__ __forceinline__ fx4 mfma16(bfx8 a, bfx8 b, fx4 c) {
  return __builtin_amdgcn_mfma_f32_16x16x32_bf16(a, b, c, 0, 0, 0);
}

// ---------------------------------------------------------------------------
// 256x256 GEMM: C[M,N] = A[M,K'] @ B^T[N,K'] (+bias,+gelu), 8 waves, BK=64.
// K' = 768 (nt=12) in all uses. 128 KiB LDS double-buffered; LDS tile
// [128][64]bf16, slot^=row&7 swizzle (conflict-free ds_read_b128, verified 0
// SQ_LDS_BANK_CONFLICT in R7). blockIdx.z = split-K slice; f32 partial out.
// flags: 1=bias, 4=gelu, 8=out bf16. N may be ragged (col guard).
// ---------------------------------------------------------------------------
__global__ __launch_bounds__(512, 1) void gemm256(
    const bh_t* __restrict__ A, const bh_t* __restrict__ B,
    const float* __restrict__ bias, void* __restrict__ outp,
    int M, int N, int K, int lda, int flags)
{
  __shared__ bh_t LA0[2][128][64], LB0[2][128][64];   // buf0: [half][row][k]
  __shared__ bh_t LA1[2][128][64], LB1[2][128][64];   // buf1
  const int tid = threadIdx.x;
  const int wid = tid >> 6, lane = tid & 63;
  const int g = lane >> 4, r16 = lane & 15;
  const int wr = wid >> 2, wc = wid & 3;              // 2M x 4N waves
  const int m0 = blockIdx.x * 256, n0 = blockIdx.y * 256;
  // swizzled k-slot offsets (elements): LDS[row][slot] holds global slot^(row&7)
  const int sw0 = ((g    ) ^ (r16 & 7)) * 8;
  const int sw1 = ((g + 4) ^ (r16 & 7)) * 8;

  const bh_t* Ab  = A + (size_t)blockIdx.z * K + (size_t)m0 * lda;
  const bh_t* Bb  = B + (size_t)blockIdx.z * K + (size_t)n0 * lda;
  const bh_t* Ab1 = Ab + (size_t)128 * lda;
  const bh_t* Bb1 = Bb + (size_t)128 * lda;
  const int nt = K >> 6;   // = 12

  fx4 acc[8][4] = {};

  // stage one 128x64 half-tile (16 KB, 2 loads/thread): dst linear, SOURCE
  // pre-swizzled with the involution slot ^= row&7 (rule: both-sides-or-neither)
  auto stageHalf = [&](bh_t* dst, const bh_t* src, int t) {
    const int k0 = t << 6;
    #pragma unroll
    for (int j = 0; j < 2; ++j) {
      const int idx = j * 512 + tid;
      const int row = idx >> 3;
      const int slot = (idx & 7) ^ (row & 7);
      gload_lds16(src + (size_t)row * lda + k0 + slot * 8, dst + (size_t)idx * 8);
    }
  };

#define LM_PHASE_MFMA(AOFS, BREG, ACCOFS)                                     \
    __builtin_amdgcn_s_barrier();                                             \
    asm volatile("s_waitcnt lgkmcnt(0)" ::: "memory");                        \
    __builtin_amdgcn_s_setprio(1);                                            \
    _Pragma("unroll")                                                         \
    for (int mi = 0; mi < 4; ++mi)                                            \
      _Pragma("unroll")                                                       \
      for (int ni = 0; ni < 4; ++ni)                                          \
        acc[(ACCOFS) + mi][ni] = mfma16(av[mi], BREG[ni], acc[(ACCOFS) + mi][ni]); \
    __builtin_amdgcn_s_setprio(0);                                            \
    __builtin_amdgcn_s_barrier();

#define LM_TILE(CA, CB, T)                                                    \
  {                                                                           \
    const bh_t* ca = &CA[wr][0][0];                                           \
    const bh_t* cb = &CB[wc >> 1][0][0] + (size_t)((wc & 1) * 64) * 64;       \
    bfx8 av[4], b0[4], b1[4];                                                 \
    /* ph1: B ks0 + A rows 0-63 ks0 -> acc[0-3] */                            \
    _Pragma("unroll")                                                         \
    for (int ni = 0; ni < 4; ++ni)                                            \
      b0[ni] = *(const bfx8*)(cb + (size_t)(ni * 16 + r16) * 64 + sw0);       \
    _Pragma("unroll")                                                         \
    for (int mi = 0; mi < 4; ++mi)                                            \
      av[mi] = *(const bfx8*)(ca + (size_t)(mi * 16 + r16) * 64 + sw0);       \
    LM_PHASE_MFMA(0, b0, 0)                                                   \
    /* ph2: A rows 64-127 ks0 -> acc[4-7] */                                  \
    _Pragma("unroll")                                                         \
    for (int mi = 0; mi < 4; ++mi)                                            \
      av[mi] = *(const bfx8*)(ca + (size_t)(64 + mi * 16 + r16) * 64 + sw0);  \
    LM_PHASE_MFMA(64, b0, 4)                                                  \
    /* ph3: B ks1 + A rows 0-63 ks1 -> acc[0-3] */                            \
    _Pragma("unroll")                                                         \
    for (int ni = 0; ni < 4; ++ni)                                            \
      b1[ni] = *(const bfx8*)(cb + (size_t)(ni * 16 + r16) * 64 + sw1);       \
    _Pragma("unroll")                                                         \
    for (int mi = 0; mi < 4; ++mi)                                            \
      av[mi] = *(const bfx8*)(ca + (size_t)(mi * 16 + r16) * 64 + sw1);       \
    LM_PHASE_MFMA(0, b1, 0)                                                   \
    /* ph4: A rows 64-127 ks1 -> acc[4-7] */                                  \
    _Pragma("unroll")                                                         \
    for (int mi = 0; mi < 4; ++mi)                                            \
      av[mi] = *(const bfx8*)(ca + (size_t)(64 + mi * 16 + r16) * 64 + sw1);  \
    LM_PHASE_MFMA(64, b1, 4)                                                  \
    /* boundary: all reads of CA/CB done (ph4 trailing barrier). Stage T+2    \
       into the vacated buffer; counted vmcnt(8) retires T+1's 8 loads.  */   \
    if ((T) + 2 < nt) {                                                       \
      stageHalf(&CA[0][0][0], Ab,  (T) + 2);                                  \
      stageHalf(&CA[1][0][0], Ab1, (T) + 2);                                  \
      stageHalf(&CB[0][0][0], Bb,  (T) + 2);                                  \
      stageHalf(&CB[1][0][0], Bb1, (T) + 2);                                  \
      asm volatile("s_waitcnt vmcnt(8)" ::: "memory");                        \
    } else if ((T) + 1 < nt) {                                                \
      asm volatile("s_waitcnt vmcnt(0)" ::: "memory");                        \
    }                                                                         \
    if ((T) + 1 < nt) {                                                       \
      __builtin_amdgcn_s_barrier();                                           \
      asm volatile("" ::: "memory");                                          \
    }                                                                         \
  }

  // prologue: tiles 0 and 1 fully staged (16 loads); wait tile 0 (vmcnt(8))
  stageHalf(&LA0[0][0][0], Ab,  0);
  stageHalf(&LA0[1][0][0], Ab1, 0);
  stageHalf(&LB0[0][0][0], Bb,  0);
  stageHalf(&LB0[1][0][0], Bb1, 0);
  stageHalf(&LA1[0][0][0], Ab,  1);
  stageHalf(&LA1[1][0][0], Ab1, 1);
  stageHalf(&LB1[0][0][0], Bb,  1);
  stageHalf(&LB1[1][0][0], Bb1, 1);
  asm volatile("s_waitcnt vmcnt(8)" ::: "memory");
  __builtin_amdgcn_s_barrier();
  asm volatile("" ::: "memory");

  for (int t = 0; t < nt; t += 2) {
    LM_TILE(LA0, LB0, t);
    LM_TILE(LA1, LB1, t + 1);
  }
#undef LM_TILE
#undef LM_PHASE_MFMA

  const bool hasBias = flags & 1, doGelu = flags & 4, outBf = flags & 8;
  float* outF = (float*)outp + (size_t)blockIdx.z * ((size_t)M * N);
  bh_t*  outB = (bh_t*)outp;
  #pragma unroll
  for (int mi = 0; mi < 8; ++mi) {
    const int rowb = m0 + wr * 128 + mi * 16 + 4 * g;
    #pragma unroll
    for (int ni = 0; ni < 4; ++ni) {
      const int col = n0 + wc * 64 + ni * 16 + r16;
      if (col >= N) continue;
      const float bv = hasBias ? bias[col] : 0.0f;
      #pragma unroll
      for (int rr = 0; rr < 4; ++rr) {
        const size_t idx = (size_t)(rowb + rr) * N + col;
        float v = acc[mi][ni][rr] + bv;
        if (doGelu) v = 0.5f * v * (1.0f + erff(v * 0.70710678118654752f));
        if (outBf) outB[idx] = (bh_t)v; else outF[idx] = v;
      }
    }
  }
}

// ---------------------------------------------------------------------------
// 128x128 GEMM (R5 3-buffer pipeline) — used for proj (split-K x4).
// flags: 1=bias, 2=residual, 4=gelu, 8=out bf16. K%96==0 (nk%3).
// ---------------------------------------------------------------------------
__global__ __launch_bounds__(256, 3) void gemm_bt(
    const bh_t* __restrict__ A, const bh_t* __restrict__ B,
    const float* __restrict__ bias, const float* __restrict__ resid,
    void* __restrict__ outp, int M, int N, int K, int lda, int flags)
{
  __shared__ bh_t As0[4][128][8], Bs0[4][128][8];
  __shared__ bh_t As1[4][128][8], Bs1[4][128][8];
  __shared__ bh_t As2[4][128][8], Bs2[4][128][8];
  const int tid  = threadIdx.x;
  const int wave = tid >> 6, lane = tid & 63;
  const int g = lane >> 4, r16 = lane & 15;
  const int m0 = blockIdx.x * 128, n0 = blockIdx.y * 128;
  const int wm = (wave >> 1) * 64, wn = (wave & 1) * 64;

  const bh_t* Ab = A;
  const bh_t* Bb = B;
  if (gridDim.z > 1) {
    Ab += (size_t)blockIdx.z * K;
    Bb += (size_t)blockIdx.z * K;
  }
  Ab += (size_t)m0 * lda;
  Bb += (size_t)n0 * lda;

  const int row0 = tid & 127, kb0 = tid >> 7;
  const int kb1 = kb0 + 2;

  fx4 acc[4][4] = {};
  const int nk = K >> 5;

  auto stageTo = [&](bh_t* AsF, bh_t* BsF, int t) {
    const int k0 = t << 5;
    gload_lds16(Ab + (size_t)row0 * lda + k0 + kb0 * 8, AsF + (size_t)(wave * 64) * 8);
    gload_lds16(Ab + (size_t)row0 * lda + k0 + kb1 * 8, AsF + (size_t)(256 + wave * 64) * 8);
    gload_lds16(Bb + (size_t)row0 * lda + k0 + kb0 * 8, BsF + (size_t)(wave * 64) * 8);
    gload_lds16(Bb + (size_t)row0 * lda + k0 + kb1 * 8, BsF + (size_t)(256 + wave * 64) * 8);
  };

#define GPT_PHASE(CURA, CURB, NXA, NXB, T)                                   \
  {                                                                          \
    if ((T) + 1 < nk) { asm volatile("s_waitcnt vmcnt(4)" ::: "memory"); }   \
    else              { asm volatile("s_waitcnt vmcnt(0)" ::: "memory"); }   \
    __builtin_amdgcn_s_barrier();                                            \
    asm volatile("" ::: "memory");                                           \
    if ((T) + 2 < nk) stageTo(&NXA[0][0][0], &NXB[0][0][0], (T) + 2);        \
    bfx8 af[4], bfr[4];                                                      \
    _Pragma("unroll")                                                        \
    for (int mi = 0; mi < 4; ++mi)                                           \
      af[mi] = *(const bfx8*)&CURA[g][wm + mi * 16 + r16][0];                \
    _Pragma("unroll")                                                        \
    for (int ni = 0; ni < 4; ++ni)                                           \
      bfr[ni] = *(const bfx8*)&CURB[g][wn + ni * 16 + r16][0];               \
    _Pragma("unroll")                                                        \
    for (int mi = 0; mi < 4; ++mi)                                           \
      _Pragma("unroll")                                                      \
      for (int ni = 0; ni < 4; ++ni)                                         \
        acc[mi][ni] = mfma16(af[mi], bfr[ni], acc[mi][ni]);                  \
  }

  stageTo(&As0[0][0][0], &Bs0[0][0][0], 0);
  stageTo(&As1[0][0][0], &Bs1[0][0][0], 1);
  for (int t = 0; t < nk; t += 3) {
    GPT_PHASE(As0, Bs0, As2, Bs2, t);
    GPT_PHASE(As1, Bs1, As0, Bs0, t + 1);
    GPT_PHASE(As2, Bs2, As1, Bs1, t + 2);
  }
#undef GPT_PHASE

  const bool hasBias = flags & 1, hasRes = flags & 2;
  const bool doGelu  = flags & 4, outBf  = flags & 8;
  float* outF = (float*)outp + (size_t)blockIdx.z * ((size_t)M * N);
  bh_t*  outB = (bh_t*)outp;
  #pragma unroll
  for (int mi = 0; mi < 4; ++mi) {
    #pragma unroll
    for (int ni = 0; ni < 4; ++ni) {
      const int col = n0 + wn + ni * 16 + r16;
      if (col >= N) continue;
      const int rowb = m0 + wm + mi * 16 + 4 * g;
      const float bv = hasBias ? bias[col] : 0.0f;
      #pragma unroll
      for (int rr = 0; rr < 4; ++rr) {
        const size_t idx = (size_t)(rowb + rr) * N + col;
        float v = acc[mi][ni][rr] + bv;
        if (doGelu) v = 0.5f * v * (1.0f + erff(v * 0.70710678118654752f));
        if (hasRes) v += resid[idx];
        if (outBf) outB[idx] = (bh_t)v; else outF[idx] = v;
      }
    }
  }
}

// ---------------------------------------------------------------------------
// fused split-K reduce + residual + LayerNorm:
//   xnew = x + bias + sum_s part[s];  x <- xnew;  out <- LN(xnew)*w + b (bf16)
// ---------------------------------------------------------------------------
__global__ __launch_bounds__(256) void skred_ln(
    const float* __restrict__ part, const float* __restrict__ bias,
    float* __restrict__ x, const float* __restrict__ w,
    const float* __restrict__ bb, bh_t* __restrict__ out, int S)
{
  const int wave = threadIdx.x >> 6, lane = threadIdx.x & 63;
  const int row = blockIdx.x * 4 + wave;
  const size_t base = (size_t)row * CDIM;
  const int off = lane * 4;
  const size_t stride = (size_t)MROWS * CDIM;

  float4 v0 = *(const float4*)(x + base + off);
  float4 v1 = *(const float4*)(x + base + 256 + off);
  float4 v2 = *(const float4*)(x + base + 512 + off);
  for (int s = 0; s < S; ++s) {
    const float* pr = part + s * stride + base;
    const float4 p0 = *(const float4*)(pr + off);
    const float4 p1 = *(const float4*)(pr + 256 + off);
    const float4 p2 = *(const float4*)(pr + 512 + off);
    v0.x += p0.x; v0.y += p0.y; v0.z += p0.z; v0.w += p0.w;
    v1.x += p1.x; v1.y += p1.y; v1.z += p1.z; v1.w += p1.w;
    v2.x += p2.x; v2.y += p2.y; v2.z += p2.z; v2.w += p2.w;
  }
  const float4 q0 = *(const float4*)(bias + off);
  const float4 q1 = *(const float4*)(bias + 256 + off);
  const float4 q2 = *(const float4*)(bias + 512 + off);
  v0.x += q0.x; v0.y += q0.y; v0.z += q0.z; v0.w += q0.w;
  v1.x += q1.x; v1.y += q1.y; v1.z += q1.z; v1.w += q1.w;
  v2.x += q2.x; v2.y += q2.y; v2.z += q2.z; v2.w += q2.w;
  *(float4*)(x + base + off) = v0;
  *(float4*)(x + base + 256 + off) = v1;
  *(float4*)(x + base + 512 + off) = v2;

  float s1 = v0.x + v0.y + v0.z + v0.w + v1.x + v1.y + v1.z + v1.w
           + v2.x + v2.y + v2.z + v2.w;
  float ss = v0.x*v0.x + v0.y*v0.y + v0.z*v0.z + v0.w*v0.w
           + v1.x*v1.x + v1.y*v1.y + v1.z*v1.z + v1.w*v1.w
           + v2.x*v2.x + v2.y*v2.y + v2.z*v2.z + v2.w*v2.w;
  #pragma unroll
  for (int d = 1; d < 64; d <<= 1) { s1 += __shfl_xor(s1, d); ss += __shfl_xor(ss, d); }
  const float mean = s1 * (1.0f / 768.0f);
  const float inv = rsqrtf(ss * (1.0f / 768.0f) - mean * mean + 1e-5f);
  bh_t* orow = out + base;

  const float4 w0 = *(const float4*)(w + off),       b0 = *(const float4*)(bb + off);
  const float4 w1 = *(const float4*)(w + 256 + off), b1 = *(const float4*)(bb + 256 + off);
  const float4 w2 = *(const float4*)(w + 512 + off), b2 = *(const float4*)(bb + 512 + off);
  bfx4 o;
  o[0] = (bh_t)((v0.x - mean) * inv * w0.x + b0.x);
  o[1] = (bh_t)((v0.y - mean) * inv * w0.y + b0.y);
  o[2] = (bh_t)((v0.z - mean) * inv * w0.z + b0.z);
  o[3] = (bh_t)((v0.w - mean) * inv * w0.w + b0.w);
  *(bfx4*)(orow + off) = o;
  o[0] = (bh_t)((v1.x - mean) * inv * w1.x + b1.x);
  o[1] = (bh_t)((v1.y - mean) * inv * w1.y + b1.y);
  o[2] = (bh_t)((v1.z - mean) * inv * w1.z + b1.z);
  o[3] = (bh_t)((v1.w - mean) * inv * w1.w + b1.w);
  *(bfx4*)(orow + 256 + off) = o;
  o[0] = (bh_t)((v2.x - mean) * inv * w2.x + b2.x);
  o[1] = (bh_t)((v2.y - mean) * inv * w2.y + b2.y);
  o[2] = (bh_t)((v2.z - mean) * inv * w2.z + b2.z);
  o[3] = (bh_t)((v2.w - mean) * inv * w2.w + b2.w);
  *(bfx4*)(orow + 512 + off) = o;
}

// ---------------------------------------------------------------------------
// Flash attention, causal. One wave per (b, h, 16 q-rows).
// ---------------------------------------------------------------------------
__global__ __launch_bounds__(256) void attn_fwd(
    const bh_t* __restrict__ qkv, const bh_t* __restrict__ vT,
    bh_t* __restrict__ outb)
{
  __shared__ bh_t P[4][16][56];
  const int wave = threadIdx.x >> 6, lane = threadIdx.x & 63;
  const int g = lane >> 4, r16 = lane & 15;
  const int gw = blockIdx.x * 4 + wave;
  const int qblk = gw & 63;
  const int bh = gw >> 6;
  const int h = bh % NHEAD, b = bh / NHEAD;
  const int qbase = qblk * 16;
  const int qidx = qbase + r16;

  const bh_t* qp = qkv + (size_t)(b * TSEQ + qbase + r16) * (3 * CDIM) + h * HDIM + 8 * g;
  const bfx8 qf0 = *(const bfx8*)qp;
  const bfx8 qf1 = *(const bfx8*)(qp + 32);

  fx4 o[4] = {};
  float m = -INFINITY, l = 0.0f;
  const int ntiles = qblk / 2 + 1;

  for (int t = 0; t < ntiles; ++t) {
    const int kv0 = t * 32;
    const bh_t* kp = qkv + (size_t)(b * TSEQ + kv0 + r16) * (3 * CDIM) + CDIM + h * HDIM + 8 * g;
    const bfx8 ka0 = *(const bfx8*)kp;
    const bfx8 ka1 = *(const bfx8*)(kp + 32);
    const bfx8 kb0 = *(const bfx8*)(kp + 16 * (3 * CDIM));
    const bfx8 kb1 = *(const bfx8*)(kp + 16 * (3 * CDIM) + 32);
    fx4 s0 = {}, s1 = {};
    s0 = mfma16(ka0, qf0, s0); s0 = mfma16(ka1, qf1, s0);   // S^T: [kv][q]
    s1 = mfma16(kb0, qf0, s1); s1 = mfma16(kb1, qf1, s1);

    float mx = -INFINITY;
    float sv0[4], sv1[4];
    #pragma unroll
    for (int rr = 0; rr < 4; ++rr) {
      const int kva = kv0 + 4 * g + rr;
      const int kvb = kva + 16;
      sv0[rr] = (kva <= qidx) ? s0[rr] * 0.125f : -INFINITY;
      sv1[rr] = (kvb <= qidx) ? s1[rr] * 0.125f : -INFINITY;
      mx = fmaxf(mx, fmaxf(sv0[rr], sv1[rr]));
    }
    mx = fmaxf(mx, __shfl_xor(mx, 16));
    mx = fmaxf(mx, __shfl_xor(mx, 32));
    const float mnew = fmaxf(m, mx);
    const float corr = __expf(m - mnew);

    float ps = 0.0f;
    float pv0[4], pv1[4];
    #pragma unroll
    for (int rr = 0; rr < 4; ++rr) {
      pv0[rr] = __expf(sv0[rr] - mnew);
      pv1[rr] = __expf(sv1[rr] - mnew);
      ps += pv0[rr] + pv1[rr];
    }
    ps += __shfl_xor(ps, 16);
    ps += __shfl_xor(ps, 32);
    l = l * corr + ps;
    m = mnew;

    #pragma unroll
    for (int rr = 0; rr < 4; ++rr) {
      const float cr = __shfl(corr, 4 * g + rr);
      o[0][rr] *= cr; o[1][rr] *= cr; o[2][rr] *= cr; o[3][rr] *= cr;
    }

    bfx4 w0, w1;
    #pragma unroll
    for (int rr = 0; rr < 4; ++rr) { w0[rr] = (bh_t)pv0[rr]; w1[rr] = (bh_t)pv1[rr]; }
    *(bfx4*)&P[wave][r16][4 * g]      = w0;
    *(bfx4*)&P[wave][r16][16 + 4 * g] = w1;
    __builtin_amdgcn_wave_barrier();
    const bfx8 pf = *(const bfx8*)&P[wave][r16][8 * g];

    #pragma unroll
    for (int fi = 0; fi < 4; ++fi) {
      const bh_t* vp = vT + (size_t)(bh * HDIM + fi * 16 + r16) * TSEQ + kv0 + 8 * g;
      const bfx8 vf = *(const bfx8*)vp;
      o[fi] = mfma16(pf, vf, o[fi]);
    }
  }

  #pragma unroll
  for (int rr = 0; rr < 4; ++rr) {
    const float lr = __shfl(l, 4 * g + rr);
    const float inv = 1.0f / lr;
    const int trow = b * TSEQ + qbase + 4 * g + rr;
    #pragma unroll
    for (int fi = 0; fi < 4; ++fi)
      outb[(size_t)trow * CDIM + h * HDIM + fi * 16 + r16] = (bh_t)(o[fi][rr] * inv);
  }
}

// ---------------------------------------------------------------------------
// LayerNorm: f32 in -> bf16 out. One wave per row. (layer 0 entry only)
// ---------------------------------------------------------------------------
__global__ __launch_bounds__(256) void ln_fwd(
    const float* __restrict__ x, const float* __restrict__ w,
    const float* __restrict__ bb, bh_t* __restrict__ out)
{
  const int wave = threadIdx.x >> 6, lane = threadIdx.x & 63;
  const int row = blockIdx.x * 4 + wave;
  const float* xr = x + (size_t)row * CDIM;
  const int off = lane * 4;
  const float4 v0 = *(const float4*)(xr + off);
  const float4 v1 = *(const float4*)(xr + 256 + off);
  const float4 v2 = *(const float4*)(xr + 512 + off);
  float s  = v0.x + v0.y + v0.z + v0.w + v1.x + v1.y + v1.z + v1.w
           + v2.x + v2.y + v2.z + v2.w;
  float ss = v0.x*v0.x + v0.y*v0.y + v0.z*v0.z + v0.w*v0.w
           + v1.x*v1.x + v1.y*v1.y + v1.z*v1.z + v1.w*v1.w
           + v2.x*v2.x + v2.y*v2.y + v2.z*v2.z + v2.w*v2.w;
  #pragma unroll
  for (int d = 1; d < 64; d <<= 1) { s += __shfl_xor(s, d); ss += __shfl_xor(ss, d); }
  const float mean = s * (1.0f / 768.0f);
  const float inv = rsqrtf(ss * (1.0f / 768.0f) - mean * mean + 1e-5f);
  bh_t* orow = out + (size_t)row * CDIM;

  const float4 w0 = *(const float4*)(w + off),  b0 = *(const float4*)(bb + off);
  const float4 w1 = *(const float4*)(w + 256 + off), b1 = *(const float4*)(bb + 256 + off);
  const float4 w2 = *(const float4*)(w + 512 + off), b2 = *(const float4*)(bb + 512 + off);
  bfx4 o;
  o[0] = (bh_t)((v0.x - mean) * inv * w0.x + b0.x);
  o[1] = (bh_t)((v0.y - mean) * inv * w0.y + b0.y);
  o[2] = (bh_t)((v0.z - mean) * inv * w0.z + b0.z);
  o[3] = (bh_t)((v0.w - mean) * inv * w0.w + b0.w);
  *(bfx4*)(orow + off) = o;
  o[0] = (bh_t)((v1.x - mean) * inv * w1.x + b1.x);
  o[1] = (bh_t)((v1.y - mean) * inv * w1.y + b1.y);
  o[2] = (bh_t)((v1.z - mean) * inv * w1.z + b1.z);
  o[3] = (bh_t)((v1.w - mean) * inv * w1.w + b1.w);
  *(bfx4*)(orow + 256 + off) = o;
  o[0] = (bh_t)((v2.x - mean) * inv * w2.x + b2.x);
  o[1] = (bh_t)((v2.y - mean) * inv * w2.y + b2.y);
  o[2] = (bh_t)((v2.z - mean) * inv * w2.z + b2.z);
  o[3] = (bh_t)((v2.w - mean) * inv * w2.w + b2.w);
  *(bfx4*)(orow + 512 + off) = o;
}

// ---------------------------------------------------------------------------
__global__ void embed_k(const int* __restrict__ ids, const float* __restrict__ tok,
                        const float* __restrict__ pos, float* __restrict__ x)
{
  const int bt = blockIdx.x;
  const int t = bt & (TSEQ - 1);
  const int id = ids[bt];
  const float* tr = tok + (size_t)id * CDIM;
  const float* pr = pos + (size_t)t * CDIM;
  float* xr = x + (size_t)bt * CDIM;
  for (int j = threadIdx.x; j < CDIM; j += 256) xr[j] = tr[j] + pr[j];
}

// transpose + f32->bf16: in [L][R][Cn] -> out [L][Cn][R]
__global__ void tconv(const float* __restrict__ in, bh_t* __restrict__ out, int R, int Cn)
{
  __shared__ float tile[32][33];
  const size_t msz = (size_t)R * Cn;
  in  += msz * blockIdx.z;
  out += msz * blockIdx.z;
  const int tx = threadIdx.x & 31, ty = threadIdx.x >> 5;
  const int c0 = blockIdx.x * 32, r0 = blockIdx.y * 32;
  #pragma unroll
  for (int i = 0; i < 32; i += 8)
    tile[ty + i][tx] = in[(size_t)(r0 + ty + i) * Cn + c0 + tx];
  __syncthreads();
  #pragma unroll
  for (int i = 0; i < 32; i += 8)
    out[(size_t)(c0 + ty + i) * R + r0 + tx] = (bh_t)tile[tx][ty + i];
}

// tok_emb f32 [V][C] -> bf16 [VPAD][C], zero-padded rows
__global__ void embconv(const float* __restrict__ in, bh_t* __restrict__ out)
{
  const size_t i4 = ((size_t)blockIdx.x * 256 + threadIdx.x) * 4;
  if (i4 >= (size_t)VPAD * CDIM) return;
  const size_t vlim = (size_t)VOCAB * CDIM;
  float4 f = make_float4(0.f, 0.f, 0.f, 0.f);
  if (i4 < vlim) f = *(const float4*)(in + i4);
  bfx4 o;
  o[0] = (bh_t)f.x; o[1] = (bh_t)f.y; o[2] = (bh_t)f.z; o[3] = (bh_t)f.w;
  *(bfx4*)(out + i4) = o;
}

// V slice of qkv -> vT[bh*64 + d][t]
__global__ void vtrans(const bh_t* __restrict__ qkv, bh_t* __restrict__ vT)
{
  __shared__ bh_t tile[32][34];
  const int bh = blockIdx.z;
  const int b = bh / NHEAD, h = bh % NHEAD;
  const int d0 = blockIdx.x * 32, t0 = blockIdx.y * 32;
  const int tx = threadIdx.x & 31, ty = threadIdx.x >> 5;
  #pragma unroll
  for (int i = 0; i < 32; i += 8)
    tile[ty + i][tx] = qkv[(size_t)(b * TSEQ + t0 + ty + i) * (3 * CDIM) + 2 * CDIM + h * HDIM + d0 + tx];
  __syncthreads();
  #pragma unroll
  for (int i = 0; i < 32; i += 8)
    vT[(size_t)(bh * HDIM + d0 + ty + i) * TSEQ + t0 + tx] = tile[tx][ty + i];
}

// ---------------------------------------------------------------------------
extern "C" void kernel_launch(void* const* d_in, const int* in_sizes, int n_in,
                              void* d_out, int out_size, void* d_ws, size_t ws_size,
                              hipStream_t stream)
{
  (void)in_sizes; (void)n_in; (void)out_size; (void)ws_size;
  const int*   ids    = (const int*)d_in[0];
  const float* tok    = (const float*)d_in[1];
  const float* pos    = (const float*)d_in[2];
  const float* qkv_w  = (const float*)d_in[3];
  const float* qkv_b  = (const float*)d_in[4];
  const float* proj_w = (const float*)d_in[5];
  const float* proj_b = (const float*)d_in[6];
  const float* ln1_w  = (const float*)d_in[7];
  const float* ln1_b  = (const float*)d_in[8];
  const float* ln2_w  = (const float*)d_in[9];
  const float* ln2_b  = (const float*)d_in[10];
  const float* fc1_w  = (const float*)d_in[11];
  const float* fc1_b  = (const float*)d_in[12];
  const float* fc2_w  = (const float*)d_in[13];
  const float* fc2_b  = (const float*)d_in[14];
  const float* lnf_w  = (const float*)d_in[15];
  const float* lnf_b  = (const float*)d_in[16];

  // ---- scratch in ws (activations + embT), ~153 MB
  char* wp = (char*)d_ws;
  auto carve = [&](size_t bytes) { char* p = wp; wp += (bytes + 255) & ~(size_t)255; return p; };
  float* x     = (float*)carve((size_t)MROWS * CDIM * 4);
  bh_t*  hbuf  = (bh_t*)carve((size_t)MROWS * CDIM * 2);
  bh_t*  qkvb  = (bh_t*)carve((size_t)MROWS * 3 * CDIM * 2);
  bh_t*  vT    = (bh_t*)carve((size_t)48 * HDIM * TSEQ * 2);
  bh_t*  attno = (bh_t*)carve((size_t)MROWS * CDIM * 2);
  bh_t*  mlp1  = (bh_t*)carve((size_t)MROWS * 3072 * 2);
  bh_t*  embT  = (bh_t*)carve((size_t)VPAD * CDIM * 2);

  // ---- staged in d_out (dead before lm_head overwrites it), ~270 MB of 823
  char* op = (char*)d_out;
  auto carveO = [&](size_t bytes) { char* p = op; op += (bytes + 255) & ~(size_t)255; return p; };
  bh_t* qkvwT  = (bh_t*)carveO((size_t)NLAYER * 3 * CDIM * CDIM * 2);
  bh_t* projwT = (bh_t*)carveO((size_t)NLAYER * CDIM * CDIM * 2);
  bh_t* fc1wT  = (bh_t*)carveO((size_t)NLAYER * 3072 * CDIM * 2);
  bh_t* fc2wT  = (bh_t*)carveO((size_t)NLAYER * CDIM * 3072 * 2);
  float* skpart = (float*)carveO((size_t)4 * MROWS * CDIM * 4);   // split-K partials

  tconv<<<dim3(2304 / 32, 768 / 32, NLAYER), 256, 0, stream>>>(qkv_w, qkvwT, 768, 2304);
  tconv<<<dim3(768 / 32, 768 / 32, NLAYER), 256, 0, stream>>>(proj_w, projwT, 768, 768);
  tconv<<<dim3(3072 / 32, 768 / 32, NLAYER), 256, 0, stream>>>(fc1_w, fc1wT, 768, 3072);
  tconv<<<dim3(768 / 32, 3072 / 32, NLAYER), 256, 0, stream>>>(fc2_w, fc2wT, 3072, 768);
  embconv<<<((VPAD * CDIM / 4) + 255) / 256, 256, 0, stream>>>(tok, embT);
  embed_k<<<MROWS, 256, 0, stream>>>(ids, tok, pos, x);

  ln_fwd<<<MROWS / 4, 256, 0, stream>>>(x, ln1_w, ln1_b, hbuf);
  for (int l = 0; l < NLAYER; ++l) {
    // qkv: 256^2, grid 16x9
    gemm256<<<dim3(16, 9), 512, 0, stream>>>(hbuf, qkvwT + (size_t)l * 3 * CDIM * CDIM,
        qkv_b + l * 3 * CDIM, qkvb, MROWS, 3 * CDIM, CDIM, CDIM, 1 | 8);
    vtrans<<<dim3(2, 32, 48), 256, 0, stream>>>(qkvb, vT);
    attn_fwd<<<768, 256, 0, stream>>>(qkvb, vT, attno);
    // proj: 128^2 split-K x4 (K_eff=192, nk=6), 768 blocks
    gemm_bt<<<dim3(32, 6, 4), 256, 0, stream>>>(attno,
        projwT + (size_t)l * CDIM * CDIM, nullptr, nullptr,
        skpart, MROWS, CDIM, 192, CDIM, 0);
    skred_ln<<<MROWS / 4, 256, 0, stream>>>(skpart, proj_b + l * CDIM, x,
        ln2_w + l * CDIM, ln2_b + l * CDIM, hbuf, 4);
    // fc1: 256^2, grid 16x12
    gemm256<<<dim3(16, 12), 512, 0, stream>>>(hbuf, fc1wT + (size_t)l * 3072 * CDIM,
        fc1_b + l * 3072, mlp1, MROWS, 3072, CDIM, CDIM, 1 | 4 | 8);
    // fc2: 256^2 split-K x4 (K_eff=768, nt=12), grid 16x3x4
    gemm256<<<dim3(16, 3, 4), 512, 0, stream>>>(mlp1, fc2wT + (size_t)l * CDIM * 3072,
        nullptr, skpart, MROWS, CDIM, 768, 3072, 0);
    const float* nw = (l + 1 < NLAYER) ? ln1_w + (l + 1) * CDIM : lnf_w;
    const float* nb = (l + 1 < NLAYER) ? ln1_b + (l + 1) * CDIM : lnf_b;
    skred_ln<<<MROWS / 4, 256, 0, stream>>>(skpart, fc2_b + l * CDIM, x, nw, nb, hbuf, 4);
  }
  gemm256<<<dim3(16, VPAD / 256), 512, 0, stream>>>(hbuf, embT, nullptr,
      (float*)d_out, MROWS, VOCAB, CDIM, CDIM, 0);
}

// Round 9
// 3822.950 us; speedup vs baseline: 1.0926x; 1.0926x over previous
//
#include <hip/hip_runtime.h>
#include <hip/hip_bf16.h>

// GPT-2 small forward on gfx950. bf16 MFMA GEMMs (f32 accum), flash attention.
// R9: gemm256 reverted to R7 schedule (R8's per-phase barriers forced wave
//     lockstep: MFMA pipe idle during ds_read windows, -12%). NEW gemm256n
//     (256x128, BK=32, 48KB LDS, ~120 regs -> 2 blocks/CU) for qkv/fc1:
//     grids 288/384 fill the machine and co-resident blocks cover the
//     per-tile vmcnt(0) drain. BK=32 swizzle: slot ^= (row>>1)&3 (2-way=free).

typedef __bf16 bh_t;
typedef __bf16 bfx4 __attribute__((ext_vector_type(4)));
typedef __bf16 bfx8 __attribute__((ext_vector_type(8)));
typedef float  fx4  __attribute__((ext_vector_type(4)));

#define CDIM 768
#define TSEQ 1024
#define NHEAD 12
#define HDIM 64
#define NLAYER 12
#define MROWS 4096          // B*T
#define VOCAB 50257
#define VPAD  50432         // 197 * 256

__device__ __forceinline__ void gload_lds16(const void* g, void* l) {
  __builtin_amdgcn_global_load_lds(
      (const __attribute__((address_space(1))) void*)g,
      (__attribute__((address_space(3))) void*)l, 16, 0, 0);
}

__device__ __forceinline__ fx4 mfma16(bfx8 a, bfx8 b, fx4 c) {
  return __builtin_amdgcn_mfma_f32_16x16x32_bf16(a, b, c, 0, 0, 0);
}

// ---------------------------------------------------------------------------
// 256x256 GEMM (R7 schedule, best measured). 8 waves, BK=64, 128KiB LDS,
// slot^=row&7 swizzle (0 bank conflicts, R7-verified). blockIdx.z = split-K.
// flags: 1=bias, 4=gelu, 8=out bf16.
// ---------------------------------------------------------------------------
__global__ __launch_bounds__(512, 1) void gemm256(
    const bh_t* __restrict__ A, const bh_t* __restrict__ B,
    const float* __restrict__ bias, void* __restrict__ outp,
    int M, int N, int K, int lda, int flags)
{
  __shared__ bh_t LA0[2][128][64], LB0[2][128][64];   // buf0: [half][row][k]
  __shared__ bh_t LA1[2][128][64], LB1[2][128][64];   // buf1
  const int tid = threadIdx.x;
  const int wid = tid >> 6, lane = tid & 63;
  const int g = lane >> 4, r16 = lane & 15;
  const int wr = wid >> 2, wc = wid & 3;              // 2M x 4N waves
  const int m0 = blockIdx.x * 256, n0 = blockIdx.y * 256;
  const int sw0 = ((g    ) ^ (r16 & 7)) * 8;
  const int sw1 = ((g + 4) ^ (r16 & 7)) * 8;

  const bh_t* Ab  = A + (size_t)blockIdx.z * K + (size_t)m0 * lda;
  const bh_t* Bb  = B + (size_t)blockIdx.z * K + (size_t)n0 * lda;
  const bh_t* Ab1 = Ab + (size_t)128 * lda;
  const bh_t* Bb1 = Bb + (size_t)128 * lda;
  const int nt = K >> 6;   // = 12

  fx4 acc[8][4] = {};

  auto stageHalf = [&](bh_t* dst, const bh_t* src, int t) {
    const int k0 = t << 6;
    #pragma unroll
    for (int j = 0; j < 2; ++j) {
      const int idx = j * 512 + tid;
      const int row = idx >> 3;
      const int slot = (idx & 7) ^ (row & 7);
      gload_lds16(src + (size_t)row * lda + k0 + slot * 8, dst + (size_t)idx * 8);
    }
  };

#define LM_TILE(CA, CB, NA, NB, T)                                            \
  {                                                                           \
    const bh_t* ca = &CA[wr][0][0];                                           \
    const bh_t* cb = &CB[wc >> 1][0][0] + (size_t)((wc & 1) * 64) * 64;       \
    bfx8 a0[4], b0[4], b1[4];                                                 \
    _Pragma("unroll")                                                         \
    for (int ni = 0; ni < 4; ++ni)                                            \
      b0[ni] = *(const bfx8*)(cb + (size_t)(ni * 16 + r16) * 64 + sw0);       \
    _Pragma("unroll")                                                         \
    for (int mi = 0; mi < 4; ++mi)                                            \
      a0[mi] = *(const bfx8*)(ca + (size_t)(mi * 16 + r16) * 64 + sw0);       \
    __builtin_amdgcn_s_setprio(1);                                            \
    _Pragma("unroll")                                                         \
    for (int mi = 0; mi < 4; ++mi)                                            \
      _Pragma("unroll")                                                       \
      for (int ni = 0; ni < 4; ++ni)                                          \
        acc[mi][ni] = mfma16(a0[mi], b0[ni], acc[mi][ni]);                    \
    __builtin_amdgcn_s_setprio(0);                                            \
    if ((T) + 1 < nt) stageHalf(&NA[1][0][0], Ab1, (T) + 1);                  \
    _Pragma("unroll")                                                         \
    for (int mi = 0; mi < 4; ++mi)                                            \
      a0[mi] = *(const bfx8*)(ca + (size_t)(64 + mi * 16 + r16) * 64 + sw0);  \
    __builtin_amdgcn_s_setprio(1);                                            \
    _Pragma("unroll")                                                         \
    for (int mi = 0; mi < 4; ++mi)                                            \
      _Pragma("unroll")                                                       \
      for (int ni = 0; ni < 4; ++ni)                                          \
        acc[4 + mi][ni] = mfma16(a0[mi], b0[ni], acc[4 + mi][ni]);            \
    __builtin_amdgcn_s_setprio(0);                                            \
    if ((T) + 1 < nt) stageHalf(&NB[0][0][0], Bb, (T) + 1);                   \
    _Pragma("unroll")                                                         \
    for (int ni = 0; ni < 4; ++ni)                                            \
      b1[ni] = *(const bfx8*)(cb + (size_t)(ni * 16 + r16) * 64 + sw1);       \
    _Pragma("unroll")                                                         \
    for (int mi = 0; mi < 4; ++mi)                                            \
      a0[mi] = *(const bfx8*)(ca + (size_t)(mi * 16 + r16) * 64 + sw1);       \
    __builtin_amdgcn_s_setprio(1);                                            \
    _Pragma("unroll")                                                         \
    for (int mi = 0; mi < 4; ++mi)                                            \
      _Pragma("unroll")                                                       \
      for (int ni = 0; ni < 4; ++ni)                                          \
        acc[mi][ni] = mfma16(a0[mi], b1[ni], acc[mi][ni]);                    \
    __builtin_amdgcn_s_setprio(0);                                            \
    if ((T) + 1 < nt) stageHalf(&NB[1][0][0], Bb1, (T) + 1);                  \
    _Pragma("unroll")                                                         \
    for (int mi = 0; mi < 4; ++mi)                                            \
      a0[mi] = *(const bfx8*)(ca + (size_t)(64 + mi * 16 + r16) * 64 + sw1);  \
    __builtin_amdgcn_s_setprio(1);                                            \
    _Pragma("unroll")                                                         \
    for (int mi = 0; mi < 4; ++mi)                                            \
      _Pragma("unroll")                                                       \
      for (int ni = 0; ni < 4; ++ni)                                          \
        acc[4 + mi][ni] = mfma16(a0[mi], b1[ni], acc[4 + mi][ni]);            \
    __builtin_amdgcn_s_setprio(0);                                            \
    asm volatile("s_waitcnt lgkmcnt(0)" ::: "memory");                        \
    __builtin_amdgcn_s_barrier();                                             \
    if ((T) + 2 < nt) {                                                       \
      stageHalf(&CA[0][0][0], Ab, (T) + 2);                                   \
      asm volatile("s_waitcnt vmcnt(2)" ::: "memory");                        \
    } else if ((T) + 1 < nt) {                                                \
      asm volatile("s_waitcnt vmcnt(0)" ::: "memory");                        \
    }                                                                         \
    __builtin_amdgcn_s_barrier();                                             \
    asm volatile("" ::: "memory");                                            \
  }

  stageHalf(&LA0[0][0][0], Ab, 0);
  stageHalf(&LA0[1][0][0], Ab1, 0);
  stageHalf(&LB0[0][0][0], Bb, 0);
  stageHalf(&LB0[1][0][0], Bb1, 0);
  stageHalf(&LA1[0][0][0], Ab, 1);
  asm volatile("s_waitcnt vmcnt(2)" ::: "memory");
  __builtin_amdgcn_s_barrier();
  asm volatile("" ::: "memory");

  for (int t = 0; t < nt; t += 2) {
    LM_TILE(LA0, LB0, LA1, LB1, t);
    LM_TILE(LA1, LB1, LA0, LB0, t + 1);
  }
#undef LM_TILE

  const bool hasBias = flags & 1, doGelu = flags & 4, outBf = flags & 8;
  float* outF = (float*)outp + (size_t)blockIdx.z * ((size_t)M * N);
  bh_t*  outB = (bh_t*)outp;
  #pragma unroll
  for (int mi = 0; mi < 8; ++mi) {
    const int rowb = m0 + wr * 128 + mi * 16 + 4 * g;
    #pragma unroll
    for (int ni = 0; ni < 4; ++ni) {
      const int col = n0 + wc * 64 + ni * 16 + r16;
      if (col >= N) continue;
      const float bv = hasBias ? bias[col] : 0.0f;
      #pragma unroll
      for (int rr = 0; rr < 4; ++rr) {
        const size_t idx = (size_t)(rowb + rr) * N + col;
        float v = acc[mi][ni][rr] + bv;
        if (doGelu) v = 0.5f * v * (1.0f + erff(v * 0.70710678118654752f));
        if (outBf) outB[idx] = (bh_t)v; else outF[idx] = v;
      }
    }
  }
}

// ---------------------------------------------------------------------------
// 256x128 GEMM, BK=32, 48KB LDS double-buffer -> 2 blocks/CU (cross-block
// overlap covers the per-tile vmcnt(0) drain). 8 waves (2M x 4N), wave tile
// 128x32, acc 8x2 (64 regs). Swizzle: slot ^= (row>>1)&3 (2-way = free).
// flags: 1=bias, 4=gelu, 8=out bf16. K % 64 == 0.
// ---------------------------------------------------------------------------
__global__ __launch_bounds__(512, 4) void gemm256n(
    const bh_t* __restrict__ A, const bh_t* __restrict__ B,
    const float* __restrict__ bias, void* __restrict__ outp,
    int M, int N, int K, int lda, int flags)
{
  __shared__ bh_t A0[256][32], B0s[128][32];
  __shared__ bh_t A1[256][32], B1s[128][32];
  const int tid = threadIdx.x;
  const int wid = tid >> 6, lane = tid & 63;
  const int g = lane >> 4, r16 = lane & 15;
  const int wr = wid >> 2, wc = wid & 3;
  const int m0 = blockIdx.x * 256, n0 = blockIdx.y * 128;
  const int swk = (g ^ ((r16 >> 1) & 3)) * 8;   // swizzled slot offset (elems)

  const bh_t* Ab = A + (size_t)m0 * lda;
  const bh_t* Bb = B + (size_t)n0 * lda;
  const int nt = K >> 5;   // 768 -> 24

  fx4 acc[8][2] = {};

  // stage tile t: A 256x32 (2 loads/thread) + B 128x32 (1 load/thread);
  // source pre-swizzled with slot ^= (row>>1)&3, dst linear.
  auto stage = [&](bh_t* dA, bh_t* dB, int t) {
    const int k0 = t << 5;
    #pragma unroll
    for (int j = 0; j < 2; ++j) {
      const int idx = j * 512 + tid;          // 16B units, 0..1023
      const int row = idx >> 2;
      const int slot = (idx & 3) ^ ((row >> 1) & 3);
      gload_lds16(Ab + (size_t)row * lda + k0 + slot * 8, dA + (size_t)idx * 8);
    }
    {
      const int idx = tid;                    // 0..511
      const int row = idx >> 2;
      const int slot = (idx & 3) ^ ((row >> 1) & 3);
      gload_lds16(Bb + (size_t)row * lda + k0 + slot * 8, dB + (size_t)idx * 8);
    }
  };

#define N_TILE(CA, CB, NA, NB, T)                                             \
  {                                                                           \
    if ((T) + 1 < nt) stage(&NA[0][0], &NB[0][0], (T) + 1);                   \
    bfx8 av[8], bv[2];                                                        \
    _Pragma("unroll")                                                         \
    for (int ni = 0; ni < 2; ++ni)                                            \
      bv[ni] = *(const bfx8*)(&CB[wc * 32 + ni * 16 + r16][0] + swk);         \
    _Pragma("unroll")                                                         \
    for (int mi = 0; mi < 8; ++mi)                                            \
      av[mi] = *(const bfx8*)(&CA[wr * 128 + mi * 16 + r16][0] + swk);        \
    asm volatile("s_waitcnt lgkmcnt(0)" ::: "memory");                        \
    __builtin_amdgcn_s_setprio(1);                                            \
    _Pragma("unroll")                                                         \
    for (int mi = 0; mi < 8; ++mi)                                            \
      _Pragma("unroll")                                                       \
      for (int ni = 0; ni < 2; ++ni)                                          \
        acc[mi][ni] = mfma16(av[mi], bv[ni], acc[mi][ni]);                    \
    __builtin_amdgcn_s_setprio(0);                                            \
    asm volatile("s_waitcnt vmcnt(0)" ::: "memory");                          \
    __builtin_amdgcn_s_barrier();                                             \
    asm volatile("" ::: "memory");                                            \
  }

  stage(&A0[0][0], &B0s[0][0], 0);
  asm volatile("s_waitcnt vmcnt(0)" ::: "memory");
  __builtin_amdgcn_s_barrier();
  asm volatile("" ::: "memory");

  for (int t = 0; t < nt; t += 2) {
    N_TILE(A0, B0s, A1, B1s, t);
    N_TILE(A1, B1s, A0, B0s, t + 1);
  }
#undef N_TILE

  const bool hasBias = flags & 1, doGelu = flags & 4, outBf = flags & 8;
  float* outF = (float*)outp;
  bh_t*  outB = (bh_t*)outp;
  #pragma unroll
  for (int mi = 0; mi < 8; ++mi) {
    const int rowb = m0 + wr * 128 + mi * 16 + 4 * g;
    #pragma unroll
    for (int ni = 0; ni < 2; ++ni) {
      const int col = n0 + wc * 32 + ni * 16 + r16;
      if (col >= N) continue;
      const float bv = hasBias ? bias[col] : 0.0f;
      #pragma unroll
      for (int rr = 0; rr < 4; ++rr) {
        const size_t idx = (size_t)(rowb + rr) * N + col;
        float v = acc[mi][ni][rr] + bv;
        if (doGelu) v = 0.5f * v * (1.0f + erff(v * 0.70710678118654752f));
        if (outBf) outB[idx] = (bh_t)v; else outF[idx] = v;
      }
    }
  }
}

// ---------------------------------------------------------------------------
// 128x128 GEMM (R5 3-buffer pipeline) — used for proj (split-K x4).
// ---------------------------------------------------------------------------
__global__ __launch_bounds__(256, 3) void gemm_bt(
    const bh_t* __restrict__ A, const bh_t* __restrict__ B,
    const float* __restrict__ bias, const float* __restrict__ resid,
    void* __restrict__ outp, int M, int N, int K, int lda, int flags)
{
  __shared__ bh_t As0[4][128][8], Bs0[4][128][8];
  __shared__ bh_t As1[4][128][8], Bs1[4][128][8];
  __shared__ bh_t As2[4][128][8], Bs2[4][128][8];
  const int tid  = threadIdx.x;
  const int wave = tid >> 6, lane = tid & 63;
  const int g = lane >> 4, r16 = lane & 15;
  const int m0 = blockIdx.x * 128, n0 = blockIdx.y * 128;
  const int wm = (wave >> 1) * 64, wn = (wave & 1) * 64;

  const bh_t* Ab = A;
  const bh_t* Bb = B;
  if (gridDim.z > 1) {
    Ab += (size_t)blockIdx.z * K;
    Bb += (size_t)blockIdx.z * K;
  }
  Ab += (size_t)m0 * lda;
  Bb += (size_t)n0 * lda;

  const int row0 = tid & 127, kb0 = tid >> 7;
  const int kb1 = kb0 + 2;

  fx4 acc[4][4] = {};
  const int nk = K >> 5;

  auto stageTo = [&](bh_t* AsF, bh_t* BsF, int t) {
    const int k0 = t << 5;
    gload_lds16(Ab + (size_t)row0 * lda + k0 + kb0 * 8, AsF + (size_t)(wave * 64) * 8);
    gload_lds16(Ab + (size_t)row0 * lda + k0 + kb1 * 8, AsF + (size_t)(256 + wave * 64) * 8);
    gload_lds16(Bb + (size_t)row0 * lda + k0 + kb0 * 8, BsF + (size_t)(wave * 64) * 8);
    gload_lds16(Bb + (size_t)row0 * lda + k0 + kb1 * 8, BsF + (size_t)(256 + wave * 64) * 8);
  };

#define GPT_PHASE(CURA, CURB, NXA, NXB, T)                                   \
  {                                                                          \
    if ((T) + 1 < nk) { asm volatile("s_waitcnt vmcnt(4)" ::: "memory"); }   \
    else              { asm volatile("s_waitcnt vmcnt(0)" ::: "memory"); }   \
    __builtin_amdgcn_s_barrier();                                            \
    asm volatile("" ::: "memory");                                           \
    if ((T) + 2 < nk) stageTo(&NXA[0][0][0], &NXB[0][0][0], (T) + 2);        \
    bfx8 af[4], bfr[4];                                                      \
    _Pragma("unroll")                                                        \
    for (int mi = 0; mi < 4; ++mi)                                           \
      af[mi] = *(const bfx8*)&CURA[g][wm + mi * 16 + r16][0];                \
    _Pragma("unroll")                                                        \
    for (int ni = 0; ni < 4; ++ni)                                           \
      bfr[ni] = *(const bfx8*)&CURB[g][wn + ni * 16 + r16][0];               \
    _Pragma("unroll")                                                        \
    for (int mi = 0; mi < 4; ++mi)                                           \
      _Pragma("unroll")                                                      \
      for (int ni = 0; ni < 4; ++ni)                                         \
        acc[mi][ni] = mfma16(af[mi], bfr[ni], acc[mi][ni]);                  \
  }

  stageTo(&As0[0][0][0], &Bs0[0][0][0], 0);
  stageTo(&As1[0][0][0], &Bs1[0][0][0], 1);
  for (int t = 0; t < nk; t += 3) {
    GPT_PHASE(As0, Bs0, As2, Bs2, t);
    GPT_PHASE(As1, Bs1, As0, Bs0, t + 1);
    GPT_PHASE(As2, Bs2, As1, Bs1, t + 2);
  }
#undef GPT_PHASE

  const bool hasBias = flags & 1, hasRes = flags & 2;
  const bool doGelu  = flags & 4, outBf  = flags & 8;
  float* outF = (float*)outp + (size_t)blockIdx.z * ((size_t)M * N);
  bh_t*  outB = (bh_t*)outp;
  #pragma unroll
  for (int mi = 0; mi < 4; ++mi) {
    #pragma unroll
    for (int ni = 0; ni < 4; ++ni) {
      const int col = n0 + wn + ni * 16 + r16;
      if (col >= N) continue;
      const int rowb = m0 + wm + mi * 16 + 4 * g;
      const float bv = hasBias ? bias[col] : 0.0f;
      #pragma unroll
      for (int rr = 0; rr < 4; ++rr) {
        const size_t idx = (size_t)(rowb + rr) * N + col;
        float v = acc[mi][ni][rr] + bv;
        if (doGelu) v = 0.5f * v * (1.0f + erff(v * 0.70710678118654752f));
        if (hasRes) v += resid[idx];
        if (outBf) outB[idx] = (bh_t)v; else outF[idx] = v;
      }
    }
  }
}

// ---------------------------------------------------------------------------
// fused split-K reduce + residual + LayerNorm
// ---------------------------------------------------------------------------
__global__ __launch_bounds__(256) void skred_ln(
    const float* __restrict__ part, const float* __restrict__ bias,
    float* __restrict__ x, const float* __restrict__ w,
    const float* __restrict__ bb, bh_t* __restrict__ out, int S)
{
  const int wave = threadIdx.x >> 6, lane = threadIdx.x & 63;
  const int row = blockIdx.x * 4 + wave;
  const size_t base = (size_t)row * CDIM;
  const int off = lane * 4;
  const size_t stride = (size_t)MROWS * CDIM;

  float4 v0 = *(const float4*)(x + base + off);
  float4 v1 = *(const float4*)(x + base + 256 + off);
  float4 v2 = *(const float4*)(x + base + 512 + off);
  for (int s = 0; s < S; ++s) {
    const float* pr = part + s * stride + base;
    const float4 p0 = *(const float4*)(pr + off);
    const float4 p1 = *(const float4*)(pr + 256 + off);
    const float4 p2 = *(const float4*)(pr + 512 + off);
    v0.x += p0.x; v0.y += p0.y; v0.z += p0.z; v0.w += p0.w;
    v1.x += p1.x; v1.y += p1.y; v1.z += p1.z; v1.w += p1.w;
    v2.x += p2.x; v2.y += p2.y; v2.z += p2.z; v2.w += p2.w;
  }
  const float4 q0 = *(const float4*)(bias + off);
  const float4 q1 = *(const float4*)(bias + 256 + off);
  const float4 q2 = *(const float4*)(bias + 512 + off);
  v0.x += q0.x; v0.y += q0.y; v0.z += q0.z; v0.w += q0.w;
  v1.x += q1.x; v1.y += q1.y; v1.z += q1.z; v1.w += q1.w;
  v2.x += q2.x; v2.y += q2.y; v2.z += q2.z; v2.w += q2.w;
  *(float4*)(x + base + off) = v0;
  *(float4*)(x + base + 256 + off) = v1;
  *(float4*)(x + base + 512 + off) = v2;

  float s1 = v0.x + v0.y + v0.z + v0.w + v1.x + v1.y + v1.z + v1.w
           + v2.x + v2.y + v2.z + v2.w;
  float ss = v0.x*v0.x + v0.y*v0.y + v0.z*v0.z + v0.w*v0.w
           + v1.x*v1.x + v1.y*v1.y + v1.z*v1.z + v1.w*v1.w
           + v2.x*v2.x + v2.y*v2.y + v2.z*v2.z + v2.w*v2.w;
  #pragma unroll
  for (int d = 1; d < 64; d <<= 1) { s1 += __shfl_xor(s1, d); ss += __shfl_xor(ss, d); }
  const float mean = s1 * (1.0f / 768.0f);
  const float inv = rsqrtf(ss * (1.0f / 768.0f) - mean * mean + 1e-5f);
  bh_t* orow = out + base;

  const float4 w0 = *(const float4*)(w + off),       b0 = *(const float4*)(bb + off);
  const float4 w1 = *(const float4*)(w + 256 + off), b1 = *(const float4*)(bb + 256 + off);
  const float4 w2 = *(const float4*)(w + 512 + off), b2 = *(const float4*)(bb + 512 + off);
  bfx4 o;
  o[0] = (bh_t)((v0.x - mean) * inv * w0.x + b0.x);
  o[1] = (bh_t)((v0.y - mean) * inv * w0.y + b0.y);
  o[2] = (bh_t)((v0.z - mean) * inv * w0.z + b0.z);
  o[3] = (bh_t)((v0.w - mean) * inv * w0.w + b0.w);
  *(bfx4*)(orow + off) = o;
  o[0] = (bh_t)((v1.x - mean) * inv * w1.x + b1.x);
  o[1] = (bh_t)((v1.y - mean) * inv * w1.y + b1.y);
  o[2] = (bh_t)((v1.z - mean) * inv * w1.z + b1.z);
  o[3] = (bh_t)((v1.w - mean) * inv * w1.w + b1.w);
  *(bfx4*)(orow + 256 + off) = o;
  o[0] = (bh_t)((v2.x - mean) * inv * w2.x + b2.x);
  o[1] = (bh_t)((v2.y - mean) * inv * w2.y + b2.y);
  o[2] = (bh_t)((v2.z - mean) * inv * w2.z + b2.z);
  o[3] = (bh_t)((v2.w - mean) * inv * w2.w + b2.w);
  *(bfx4*)(orow + 512 + off) = o;
}

// ---------------------------------------------------------------------------
// Flash attention, causal. One wave per (b, h, 16 q-rows).
// ---------------------------------------------------------------------------
__global__ __launch_bounds__(256) void attn_fwd(
    const bh_t* __restrict__ qkv, const bh_t* __restrict__ vT,
    bh_t* __restrict__ outb)
{
  __shared__ bh_t P[4][16][56];
  const int wave = threadIdx.x >> 6, lane = threadIdx.x & 63;
  const int g = lane >> 4, r16 = lane & 15;
  const int gw = blockIdx.x * 4 + wave;
  const int qblk = gw & 63;
  const int bh = gw >> 6;
  const int h = bh % NHEAD, b = bh / NHEAD;
  const int qbase = qblk * 16;
  const int qidx = qbase + r16;

  const bh_t* qp = qkv + (size_t)(b * TSEQ + qbase + r16) * (3 * CDIM) + h * HDIM + 8 * g;
  const bfx8 qf0 = *(const bfx8*)qp;
  const bfx8 qf1 = *(const bfx8*)(qp + 32);

  fx4 o[4] = {};
  float m = -INFINITY, l = 0.0f;
  const int ntiles = qblk / 2 + 1;

  for (int t = 0; t < ntiles; ++t) {
    const int kv0 = t * 32;
    const bh_t* kp = qkv + (size_t)(b * TSEQ + kv0 + r16) * (3 * CDIM) + CDIM + h * HDIM + 8 * g;
    const bfx8 ka0 = *(const bfx8*)kp;
    const bfx8 ka1 = *(const bfx8*)(kp + 32);
    const bfx8 kb0 = *(const bfx8*)(kp + 16 * (3 * CDIM));
    const bfx8 kb1 = *(const bfx8*)(kp + 16 * (3 * CDIM) + 32);
    fx4 s0 = {}, s1 = {};
    s0 = mfma16(ka0, qf0, s0); s0 = mfma16(ka1, qf1, s0);   // S^T: [kv][q]
    s1 = mfma16(kb0, qf0, s1); s1 = mfma16(kb1, qf1, s1);

    float mx = -INFINITY;
    float sv0[4], sv1[4];
    #pragma unroll
    for (int rr = 0; rr < 4; ++rr) {
      const int kva = kv0 + 4 * g + rr;
      const int kvb = kva + 16;
      sv0[rr] = (kva <= qidx) ? s0[rr] * 0.125f : -INFINITY;
      sv1[rr] = (kvb <= qidx) ? s1[rr] * 0.125f : -INFINITY;
      mx = fmaxf(mx, fmaxf(sv0[rr], sv1[rr]));
    }
    mx = fmaxf(mx, __shfl_xor(mx, 16));
    mx = fmaxf(mx, __shfl_xor(mx, 32));
    const float mnew = fmaxf(m, mx);
    const float corr = __expf(m - mnew);

    float ps = 0.0f;
    float pv0[4], pv1[4];
    #pragma unroll
    for (int rr = 0; rr < 4; ++rr) {
      pv0[rr] = __expf(sv0[rr] - mnew);
      pv1[rr] = __expf(sv1[rr] - mnew);
      ps += pv0[rr] + pv1[rr];
    }
    ps += __shfl_xor(ps, 16);
    ps += __shfl_xor(ps, 32);
    l = l * corr + ps;
    m = mnew;

    #pragma unroll
    for (int rr = 0; rr < 4; ++rr) {
      const float cr = __shfl(corr, 4 * g + rr);
      o[0][rr] *= cr; o[1][rr] *= cr; o[2][rr] *= cr; o[3][rr] *= cr;
    }

    bfx4 w0, w1;
    #pragma unroll
    for (int rr = 0; rr < 4; ++rr) { w0[rr] = (bh_t)pv0[rr]; w1[rr] = (bh_t)pv1[rr]; }
    *(bfx4*)&P[wave][r16][4 * g]      = w0;
    *(bfx4*)&P[wave][r16][16 + 4 * g] = w1;
    __builtin_amdgcn_wave_barrier();
    const bfx8 pf = *(const bfx8*)&P[wave][r16][8 * g];

    #pragma unroll
    for (int fi = 0; fi < 4; ++fi) {
      const bh_t* vp = vT + (size_t)(bh * HDIM + fi * 16 + r16) * TSEQ + kv0 + 8 * g;
      const bfx8 vf = *(const bfx8*)vp;
      o[fi] = mfma16(pf, vf, o[fi]);
    }
  }

  #pragma unroll
  for (int rr = 0; rr < 4; ++rr) {
    const float lr = __shfl(l, 4 * g + rr);
    const float inv = 1.0f / lr;
    const int trow = b * TSEQ + qbase + 4 * g + rr;
    #pragma unroll
    for (int fi = 0; fi < 4; ++fi)
      outb[(size_t)trow * CDIM + h * HDIM + fi * 16 + r16] = (bh_t)(o[fi][rr] * inv);
  }
}

// ---------------------------------------------------------------------------
// LayerNorm: f32 in -> bf16 out. One wave per row. (layer 0 entry only)
// ---------------------------------------------------------------------------
__global__ __launch_bounds__(256) void ln_fwd(
    const float* __restrict__ x, const float* __restrict__ w,
    const float* __restrict__ bb, bh_t* __restrict__ out)
{
  const int wave = threadIdx.x >> 6, lane = threadIdx.x & 63;
  const int row = blockIdx.x * 4 + wave;
  const float* xr = x + (size_t)row * CDIM;
  const int off = lane * 4;
  const float4 v0 = *(const float4*)(xr + off);
  const float4 v1 = *(const float4*)(xr + 256 + off);
  const float4 v2 = *(const float4*)(xr + 512 + off);
  float s  = v0.x + v0.y + v0.z + v0.w + v1.x + v1.y + v1.z + v1.w
           + v2.x + v2.y + v2.z + v2.w;
  float ss = v0.x*v0.x + v0.y*v0.y + v0.z*v0.z + v0.w*v0.w
           + v1.x*v1.x + v1.y*v1.y + v1.z*v1.z + v1.w*v1.w
           + v2.x*v2.x + v2.y*v2.y + v2.z*v2.z + v2.w*v2.w;
  #pragma unroll
  for (int d = 1; d < 64; d <<= 1) { s += __shfl_xor(s, d); ss += __shfl_xor(ss, d); }
  const float mean = s * (1.0f / 768.0f);
  const float inv = rsqrtf(ss * (1.0f / 768.0f) - mean * mean + 1e-5f);
  bh_t* orow = out + (size_t)row * CDIM;

  const float4 w0 = *(const float4*)(w + off),  b0 = *(const float4*)(bb + off);
  const float4 w1 = *(const float4*)(w + 256 + off), b1 = *(const float4*)(bb + 256 + off);
  const float4 w2 = *(const float4*)(w + 512 + off), b2 = *(const float4*)(bb + 512 + off);
  bfx4 o;
  o[0] = (bh_t)((v0.x - mean) * inv * w0.x + b0.x);
  o[1] = (bh_t)((v0.y - mean) * inv * w0.y + b0.y);
  o[2] = (bh_t)((v0.z - mean) * inv * w0.z + b0.z);
  o[3] = (bh_t)((v0.w - mean) * inv * w0.w + b0.w);
  *(bfx4*)(orow + off) = o;
  o[0] = (bh_t)((v1.x - mean) * inv * w1.x + b1.x);
  o[1] = (bh_t)((v1.y - mean) * inv * w1.y + b1.y);
  o[2] = (bh_t)((v1.z - mean) * inv * w1.z + b1.z);
  o[3] = (bh_t)((v1.w - mean) * inv * w1.w + b1.w);
  *(bfx4*)(orow + 256 + off) = o;
  o[0] = (bh_t)((v2.x - mean) * inv * w2.x + b2.x);
  o[1] = (bh_t)((v2.y - mean) * inv * w2.y + b2.y);
  o[2] = (bh_t)((v2.z - mean) * inv * w2.z + b2.z);
  o[3] = (bh_t)((v2.w - mean) * inv * w2.w + b2.w);
  *(bfx4*)(orow + 512 + off) = o;
}

// ---------------------------------------------------------------------------
__global__ void embed_k(const int* __restrict__ ids, const float* __restrict__ tok,
                        const float* __restrict__ pos, float* __restrict__ x)
{
  const int bt = blockIdx.x;
  const int t = bt & (TSEQ - 1);
  const int id = ids[bt];
  const float* tr = tok + (size_t)id * CDIM;
  const float* pr = pos + (size_t)t * CDIM;
  float* xr = x + (size_t)bt * CDIM;
  for (int j = threadIdx.x; j < CDIM; j += 256) xr[j] = tr[j] + pr[j];
}

// transpose + f32->bf16: in [L][R][Cn] -> out [L][Cn][R]
__global__ void tconv(const float* __restrict__ in, bh_t* __restrict__ out, int R, int Cn)
{
  __shared__ float tile[32][33];
  const size_t msz = (size_t)R * Cn;
  in  += msz * blockIdx.z;
  out += msz * blockIdx.z;
  const int tx = threadIdx.x & 31, ty = threadIdx.x >> 5;
  const int c0 = blockIdx.x * 32, r0 = blockIdx.y * 32;
  #pragma unroll
  for (int i = 0; i < 32; i += 8)
    tile[ty + i][tx] = in[(size_t)(r0 + ty + i) * Cn + c0 + tx];
  __syncthreads();
  #pragma unroll
  for (int i = 0; i < 32; i += 8)
    out[(size_t)(c0 + ty + i) * R + r0 + tx] = (bh_t)tile[tx][ty + i];
}

// tok_emb f32 [V][C] -> bf16 [VPAD][C], zero-padded rows
__global__ void embconv(const float* __restrict__ in, bh_t* __restrict__ out)
{
  const size_t i4 = ((size_t)blockIdx.x * 256 + threadIdx.x) * 4;
  if (i4 >= (size_t)VPAD * CDIM) return;
  const size_t vlim = (size_t)VOCAB * CDIM;
  float4 f = make_float4(0.f, 0.f, 0.f, 0.f);
  if (i4 < vlim) f = *(const float4*)(in + i4);
  bfx4 o;
  o[0] = (bh_t)f.x; o[1] = (bh_t)f.y; o[2] = (bh_t)f.z; o[3] = (bh_t)f.w;
  *(bfx4*)(out + i4) = o;
}

// V slice of qkv -> vT[bh*64 + d][t]
__global__ void vtrans(const bh_t* __restrict__ qkv, bh_t* __restrict__ vT)
{
  __shared__ bh_t tile[32][34];
  const int bh = blockIdx.z;
  const int b = bh / NHEAD, h = bh % NHEAD;
  const int d0 = blockIdx.x * 32, t0 = blockIdx.y * 32;
  const int tx = threadIdx.x & 31, ty = threadIdx.x >> 5;
  #pragma unroll
  for (int i = 0; i < 32; i += 8)
    tile[ty + i][tx] = qkv[(size_t)(b * TSEQ + t0 + ty + i) * (3 * CDIM) + 2 * CDIM + h * HDIM + d0 + tx];
  __syncthreads();
  #pragma unroll
  for (int i = 0; i < 32; i += 8)
    vT[(size_t)(bh * HDIM + d0 + ty + i) * TSEQ + t0 + tx] = tile[tx][ty + i];
}

// ---------------------------------------------------------------------------
extern "C" void kernel_launch(void* const* d_in, const int* in_sizes, int n_in,
                              void* d_out, int out_size, void* d_ws, size_t ws_size,
                              hipStream_t stream)
{
  (void)in_sizes; (void)n_in; (void)out_size; (void)ws_size;
  const int*   ids    = (const int*)d_in[0];
  const float* tok    = (const float*)d_in[1];
  const float* pos    = (const float*)d_in[2];
  const float* qkv_w  = (const float*)d_in[3];
  const float* qkv_b  = (const float*)d_in[4];
  const float* proj_w = (const float*)d_in[5];
  const float* proj_b = (const float*)d_in[6];
  const float* ln1_w  = (const float*)d_in[7];
  const float* ln1_b  = (const float*)d_in[8];
  const float* ln2_w  = (const float*)d_in[9];
  const float* ln2_b  = (const float*)d_in[10];
  const float* fc1_w  = (const float*)d_in[11];
  const float* fc1_b  = (const float*)d_in[12];
  const float* fc2_w  = (const float*)d_in[13];
  const float* fc2_b  = (const float*)d_in[14];
  const float* lnf_w  = (const float*)d_in[15];
  const float* lnf_b  = (const float*)d_in[16];

  // ---- scratch in ws (activations + embT), ~153 MB
  char* wp = (char*)d_ws;
  auto carve = [&](size_t bytes) { char* p = wp; wp += (bytes + 255) & ~(size_t)255; return p; };
  float* x     = (float*)carve((size_t)MROWS * CDIM * 4);
  bh_t*  hbuf  = (bh_t*)carve((size_t)MROWS * CDIM * 2);
  bh_t*  qkvb  = (bh_t*)carve((size_t)MROWS * 3 * CDIM * 2);
  bh_t*  vT    = (bh_t*)carve((size_t)48 * HDIM * TSEQ * 2);
  bh_t*  attno = (bh_t*)carve((size_t)MROWS * CDIM * 2);
  bh_t*  mlp1  = (bh_t*)carve((size_t)MROWS * 3072 * 2);
  bh_t*  embT  = (bh_t*)carve((size_t)VPAD * CDIM * 2);

  // ---- staged in d_out (dead before lm_head overwrites it), ~270 MB of 823
  char* op = (char*)d_out;
  auto carveO = [&](size_t bytes) { char* p = op; op += (bytes + 255) & ~(size_t)255; return p; };
  bh_t* qkvwT  = (bh_t*)carveO((size_t)NLAYER * 3 * CDIM * CDIM * 2);
  bh_t* projwT = (bh_t*)carveO((size_t)NLAYER * CDIM * CDIM * 2);
  bh_t* fc1wT  = (bh_t*)carveO((size_t)NLAYER * 3072 * CDIM * 2);
  bh_t* fc2wT  = (bh_t*)carveO((size_t)NLAYER * CDIM * 3072 * 2);
  float* skpart = (float*)carveO((size_t)4 * MROWS * CDIM * 4);   // split-K partials

  tconv<<<dim3(2304 / 32, 768 / 32, NLAYER), 256, 0, stream>>>(qkv_w, qkvwT, 768, 2304);
  tconv<<<dim3(768 / 32, 768 / 32, NLAYER), 256, 0, stream>>>(proj_w, projwT, 768, 768);
  tconv<<<dim3(3072 / 32, 768 / 32, NLAYER), 256, 0, stream>>>(fc1_w, fc1wT, 768, 3072);
  tconv<<<dim3(768 / 32, 3072 / 32, NLAYER), 256, 0, stream>>>(fc2_w, fc2wT, 3072, 768);
  embconv<<<((VPAD * CDIM / 4) + 255) / 256, 256, 0, stream>>>(tok, embT);
  embed_k<<<MROWS, 256, 0, stream>>>(ids, tok, pos, x);

  ln_fwd<<<MROWS / 4, 256, 0, stream>>>(x, ln1_w, ln1_b, hbuf);
  for (int l = 0; l < NLAYER; ++l) {
    // qkv: 256x128 kernel, grid 16x18 = 288 blocks, 2 blocks/CU
    gemm256n<<<dim3(16, 18), 512, 0, stream>>>(hbuf, qkvwT + (size_t)l * 3 * CDIM * CDIM,
        qkv_b + l * 3 * CDIM, qkvb, MROWS, 3 * CDIM, CDIM, CDIM, 1 | 8);
    vtrans<<<dim3(2, 32, 48), 256, 0, stream>>>(qkvb, vT);
    attn_fwd<<<768, 256, 0, stream>>>(qkvb, vT, attno);
    // proj: 128^2 split-K x4 (K_eff=192, nk=6), 768 blocks
    gemm_bt<<<dim3(32, 6, 4), 256, 0, stream>>>(attno,
        projwT + (size_t)l * CDIM * CDIM, nullptr, nullptr,
        skpart, MROWS, CDIM, 192, CDIM, 0);
    skred_ln<<<MROWS / 4, 256, 0, stream>>>(skpart, proj_b + l * CDIM, x,
        ln2_w + l * CDIM, ln2_b + l * CDIM, hbuf, 4);
    // fc1: 256x128 kernel, grid 16x24 = 384 blocks
    gemm256n<<<dim3(16, 24), 512, 0, stream>>>(hbuf, fc1wT + (size_t)l * 3072 * CDIM,
        fc1_b + l * 3072, mlp1, MROWS, 3072, CDIM, CDIM, 1 | 4 | 8);
    // fc2: 256^2 split-K x4 (K_eff=768, nt=12), grid 16x3x4
    gemm256<<<dim3(16, 3, 4), 512, 0, stream>>>(mlp1, fc2wT + (size_t)l * CDIM * 3072,
        nullptr, skpart, MROWS, CDIM, 768, 3072, 0);
    const float* nw = (l + 1 < NLAYER) ? ln1_w + (l + 1) * CDIM : lnf_w;
    const float* nb = (l + 1 < NLAYER) ? ln1_b + (l + 1) * CDIM : lnf_b;
    skred_ln<<<MROWS / 4, 256, 0, stream>>>(skpart, fc2_b + l * CDIM, x, nw, nb, hbuf, 4);
  }
  gemm256<<<dim3(16, VPAD / 256), 512, 0, stream>>>(hbuf, embT, nullptr,
      (float*)d_out, MROWS, VOCAB, CDIM, CDIM, 0);
}

// Round 10
// 3683.376 us; speedup vs baseline: 1.1340x; 1.0379x over previous
//
#include <hip/hip_runtime.h>
#include <hip/hip_bf16.h>

// GPT-2 small forward on gfx950. bf16 MFMA GEMMs (f32 accum), flash attention.
// R10: gemm256n (256x128, BK=32, 2 blocks/CU — best-validated structure,
//      beat gemm256 on identical shapes at qkv/fc1) extended with split-K
//      and used for ALL GEMMs: qkv, proj(x4), fc1, fc2(x4), lm_head.
//      gemm256/gemm_bt removed. Mechanism: 2 blocks/CU cross-block overlap
//      covers the per-tile vmcnt(0) drain (m114 implicit wave overlap).

typedef __bf16 bh_t;
typedef __bf16 bfx4 __attribute__((ext_vector_type(4)));
typedef __bf16 bfx8 __attribute__((ext_vector_type(8)));
typedef float  fx4  __attribute__((ext_vector_type(4)));

#define CDIM 768
#define TSEQ 1024
#define NHEAD 12
#define HDIM 64
#define NLAYER 12
#define MROWS 4096          // B*T
#define VOCAB 50257
#define VPAD  50432

__device__ __forceinline__ void gload_lds16(const void* g, void* l) {
  __builtin_amdgcn_global_load_lds(
      (const __attribute__((address_space(1))) void*)g,
      (__attribute__((address_space(3))) void*)l, 16, 0, 0);
}

__device__ __forceinline__ fx4 mfma16(bfx8 a, bfx8 b, fx4 c) {
  return __builtin_amdgcn_mfma_f32_16x16x32_bf16(a, b, c, 0, 0, 0);
}

// ---------------------------------------------------------------------------
// 256x128 GEMM, BK=32, 48KB LDS double-buffer, 2 blocks/CU. 8 waves (2Mx4N),
// wave tile 128x32, acc 8x2. Swizzle slot ^= (row>>1)&3 (2 lanes/bank = free).
// blockIdx.z = split-K slice (A,B advance z*K; f32 partial at z*M*N).
// flags: 1=bias, 4=gelu, 8=out bf16. K % 64 == 0. N ragged OK (col guard).
// ---------------------------------------------------------------------------
__global__ __launch_bounds__(512, 4) void gemm256n(
    const bh_t* __restrict__ A, const bh_t* __restrict__ B,
    const float* __restrict__ bias, void* __restrict__ outp,
    int M, int N, int K, int lda, int flags)
{
  __shared__ bh_t A0[256][32], B0s[128][32];
  __shared__ bh_t A1[256][32], B1s[128][32];
  const int tid = threadIdx.x;
  const int wid = tid >> 6, lane = tid & 63;
  const int g = lane >> 4, r16 = lane & 15;
  const int wr = wid >> 2, wc = wid & 3;
  const int m0 = blockIdx.x * 256, n0 = blockIdx.y * 128;
  const int swk = (g ^ ((r16 >> 1) & 3)) * 8;   // swizzled slot offset (elems)

  const bh_t* Ab = A + (size_t)blockIdx.z * K + (size_t)m0 * lda;
  const bh_t* Bb = B + (size_t)blockIdx.z * K + (size_t)n0 * lda;
  const int nt = K >> 5;

  fx4 acc[8][2] = {};

  // stage tile t: A 256x32 (2 loads/thread) + B 128x32 (1 load/thread);
  // source pre-swizzled with slot ^= (row>>1)&3, dst linear (both-sides rule).
  auto stage = [&](bh_t* dA, bh_t* dB, int t) {
    const int k0 = t << 5;
    #pragma unroll
    for (int j = 0; j < 2; ++j) {
      const int idx = j * 512 + tid;          // 16B units, 0..1023
      const int row = idx >> 2;
      const int slot = (idx & 3) ^ ((row >> 1) & 3);
      gload_lds16(Ab + (size_t)row * lda + k0 + slot * 8, dA + (size_t)idx * 8);
    }
    {
      const int idx = tid;                    // 0..511
      const int row = idx >> 2;
      const int slot = (idx & 3) ^ ((row >> 1) & 3);
      gload_lds16(Bb + (size_t)row * lda + k0 + slot * 8, dB + (size_t)idx * 8);
    }
  };

#define N_TILE(CA, CB, NA, NB, T)                                             \
  {                                                                           \
    if ((T) + 1 < nt) stage(&NA[0][0], &NB[0][0], (T) + 1);                   \
    bfx8 av[8], bv[2];                                                        \
    _Pragma("unroll")                                                         \
    for (int ni = 0; ni < 2; ++ni)                                            \
      bv[ni] = *(const bfx8*)(&CB[wc * 32 + ni * 16 + r16][0] + swk);         \
    _Pragma("unroll")                                                         \
    for (int mi = 0; mi < 8; ++mi)                                            \
      av[mi] = *(const bfx8*)(&CA[wr * 128 + mi * 16 + r16][0] + swk);        \
    asm volatile("s_waitcnt lgkmcnt(0)" ::: "memory");                        \
    __builtin_amdgcn_s_setprio(1);                                            \
    _Pragma("unroll")                                                         \
    for (int mi = 0; mi < 8; ++mi)                                            \
      _Pragma("unroll")                                                       \
      for (int ni = 0; ni < 2; ++ni)                                          \
        acc[mi][ni] = mfma16(av[mi], bv[ni], acc[mi][ni]);                    \
    __builtin_amdgcn_s_setprio(0);                                            \
    asm volatile("s_waitcnt vmcnt(0)" ::: "memory");                          \
    __builtin_amdgcn_s_barrier();                                             \
    asm volatile("" ::: "memory");                                            \
  }

  stage(&A0[0][0], &B0s[0][0], 0);
  asm volatile("s_waitcnt vmcnt(0)" ::: "memory");
  __builtin_amdgcn_s_barrier();
  asm volatile("" ::: "memory");

  for (int t = 0; t < nt; t += 2) {
    N_TILE(A0, B0s, A1, B1s, t);
    N_TILE(A1, B1s, A0, B0s, t + 1);
  }
#undef N_TILE

  const bool hasBias = flags & 1, doGelu = flags & 4, outBf = flags & 8;
  float* outF = (float*)outp + (size_t)blockIdx.z * ((size_t)M * N);
  bh_t*  outB = (bh_t*)outp;
  #pragma unroll
  for (int mi = 0; mi < 8; ++mi) {
    const int rowb = m0 + wr * 128 + mi * 16 + 4 * g;
    #pragma unroll
    for (int ni = 0; ni < 2; ++ni) {
      const int col = n0 + wc * 32 + ni * 16 + r16;
      if (col >= N) continue;
      const float bv = hasBias ? bias[col] : 0.0f;
      #pragma unroll
      for (int rr = 0; rr < 4; ++rr) {
        const size_t idx = (size_t)(rowb + rr) * N + col;
        float v = acc[mi][ni][rr] + bv;
        if (doGelu) v = 0.5f * v * (1.0f + erff(v * 0.70710678118654752f));
        if (outBf) outB[idx] = (bh_t)v; else outF[idx] = v;
      }
    }
  }
}

// ---------------------------------------------------------------------------
// fused split-K reduce + residual + LayerNorm
// ---------------------------------------------------------------------------
__global__ __launch_bounds__(256) void skred_ln(
    const float* __restrict__ part, const float* __restrict__ bias,
    float* __restrict__ x, const float* __restrict__ w,
    const float* __restrict__ bb, bh_t* __restrict__ out, int S)
{
  const int wave = threadIdx.x >> 6, lane = threadIdx.x & 63;
  const int row = blockIdx.x * 4 + wave;
  const size_t base = (size_t)row * CDIM;
  const int off = lane * 4;
  const size_t stride = (size_t)MROWS * CDIM;

  float4 v0 = *(const float4*)(x + base + off);
  float4 v1 = *(const float4*)(x + base + 256 + off);
  float4 v2 = *(const float4*)(x + base + 512 + off);
  for (int s = 0; s < S; ++s) {
    const float* pr = part + s * stride + base;
    const float4 p0 = *(const float4*)(pr + off);
    const float4 p1 = *(const float4*)(pr + 256 + off);
    const float4 p2 = *(const float4*)(pr + 512 + off);
    v0.x += p0.x; v0.y += p0.y; v0.z += p0.z; v0.w += p0.w;
    v1.x += p1.x; v1.y += p1.y; v1.z += p1.z; v1.w += p1.w;
    v2.x += p2.x; v2.y += p2.y; v2.z += p2.z; v2.w += p2.w;
  }
  const float4 q0 = *(const float4*)(bias + off);
  const float4 q1 = *(const float4*)(bias + 256 + off);
  const float4 q2 = *(const float4*)(bias + 512 + off);
  v0.x += q0.x; v0.y += q0.y; v0.z += q0.z; v0.w += q0.w;
  v1.x += q1.x; v1.y += q1.y; v1.z += q1.z; v1.w += q1.w;
  v2.x += q2.x; v2.y += q2.y; v2.z += q2.z; v2.w += q2.w;
  *(float4*)(x + base + off) = v0;
  *(float4*)(x + base + 256 + off) = v1;
  *(float4*)(x + base + 512 + off) = v2;

  float s1 = v0.x + v0.y + v0.z + v0.w + v1.x + v1.y + v1.z + v1.w
           + v2.x + v2.y + v2.z + v2.w;
  float ss = v0.x*v0.x + v0.y*v0.y + v0.z*v0.z + v0.w*v0.w
           + v1.x*v1.x + v1.y*v1.y + v1.z*v1.z + v1.w*v1.w
           + v2.x*v2.x + v2.y*v2.y + v2.z*v2.z + v2.w*v2.w;
  #pragma unroll
  for (int d = 1; d < 64; d <<= 1) { s1 += __shfl_xor(s1, d); ss += __shfl_xor(ss, d); }
  const float mean = s1 * (1.0f / 768.0f);
  const float inv = rsqrtf(ss * (1.0f / 768.0f) - mean * mean + 1e-5f);
  bh_t* orow = out + base;

  const float4 w0 = *(const float4*)(w + off),       b0 = *(const float4*)(bb + off);
  const float4 w1 = *(const float4*)(w + 256 + off), b1 = *(const float4*)(bb + 256 + off);
  const float4 w2 = *(const float4*)(w + 512 + off), b2 = *(const float4*)(bb + 512 + off);
  bfx4 o;
  o[0] = (bh_t)((v0.x - mean) * inv * w0.x + b0.x);
  o[1] = (bh_t)((v0.y - mean) * inv * w0.y + b0.y);
  o[2] = (bh_t)((v0.z - mean) * inv * w0.z + b0.z);
  o[3] = (bh_t)((v0.w - mean) * inv * w0.w + b0.w);
  *(bfx4*)(orow + off) = o;
  o[0] = (bh_t)((v1.x - mean) * inv * w1.x + b1.x);
  o[1] = (bh_t)((v1.y - mean) * inv * w1.y + b1.y);
  o[2] = (bh_t)((v1.z - mean) * inv * w1.z + b1.z);
  o[3] = (bh_t)((v1.w - mean) * inv * w1.w + b1.w);
  *(bfx4*)(orow + 256 + off) = o;
  o[0] = (bh_t)((v2.x - mean) * inv * w2.x + b2.x);
  o[1] = (bh_t)((v2.y - mean) * inv * w2.y + b2.y);
  o[2] = (bh_t)((v2.z - mean) * inv * w2.z + b2.z);
  o[3] = (bh_t)((v2.w - mean) * inv * w2.w + b2.w);
  *(bfx4*)(orow + 512 + off) = o;
}

// ---------------------------------------------------------------------------
// Flash attention, causal. One wave per (b, h, 16 q-rows).
// ---------------------------------------------------------------------------
__global__ __launch_bounds__(256) void attn_fwd(
    const bh_t* __restrict__ qkv, const bh_t* __restrict__ vT,
    bh_t* __restrict__ outb)
{
  __shared__ bh_t P[4][16][56];
  const int wave = threadIdx.x >> 6, lane = threadIdx.x & 63;
  const int g = lane >> 4, r16 = lane & 15;
  const int gw = blockIdx.x * 4 + wave;
  const int qblk = gw & 63;
  const int bh = gw >> 6;
  const int h = bh % NHEAD, b = bh / NHEAD;
  const int qbase = qblk * 16;
  const int qidx = qbase + r16;

  const bh_t* qp = qkv + (size_t)(b * TSEQ + qbase + r16) * (3 * CDIM) + h * HDIM + 8 * g;
  const bfx8 qf0 = *(const bfx8*)qp;
  const bfx8 qf1 = *(const bfx8*)(qp + 32);

  fx4 o[4] = {};
  float m = -INFINITY, l = 0.0f;
  const int ntiles = qblk / 2 + 1;

  for (int t = 0; t < ntiles; ++t) {
    const int kv0 = t * 32;
    const bh_t* kp = qkv + (size_t)(b * TSEQ + kv0 + r16) * (3 * CDIM) + CDIM + h * HDIM + 8 * g;
    const bfx8 ka0 = *(const bfx8*)kp;
    const bfx8 ka1 = *(const bfx8*)(kp + 32);
    const bfx8 kb0 = *(const bfx8*)(kp + 16 * (3 * CDIM));
    const bfx8 kb1 = *(const bfx8*)(kp + 16 * (3 * CDIM) + 32);
    fx4 s0 = {}, s1 = {};
    s0 = mfma16(ka0, qf0, s0); s0 = mfma16(ka1, qf1, s0);   // S^T: [kv][q]
    s1 = mfma16(kb0, qf0, s1); s1 = mfma16(kb1, qf1, s1);

    float mx = -INFINITY;
    float sv0[4], sv1[4];
    #pragma unroll
    for (int rr = 0; rr < 4; ++rr) {
      const int kva = kv0 + 4 * g + rr;
      const int kvb = kva + 16;
      sv0[rr] = (kva <= qidx) ? s0[rr] * 0.125f : -INFINITY;
      sv1[rr] = (kvb <= qidx) ? s1[rr] * 0.125f : -INFINITY;
      mx = fmaxf(mx, fmaxf(sv0[rr], sv1[rr]));
    }
    mx = fmaxf(mx, __shfl_xor(mx, 16));
    mx = fmaxf(mx, __shfl_xor(mx, 32));
    const float mnew = fmaxf(m, mx);
    const float corr = __expf(m - mnew);

    float ps = 0.0f;
    float pv0[4], pv1[4];
    #pragma unroll
    for (int rr = 0; rr < 4; ++rr) {
      pv0[rr] = __expf(sv0[rr] - mnew);
      pv1[rr] = __expf(sv1[rr] - mnew);
      ps += pv0[rr] + pv1[rr];
    }
    ps += __shfl_xor(ps, 16);
    ps += __shfl_xor(ps, 32);
    l = l * corr + ps;
    m = mnew;

    #pragma unroll
    for (int rr = 0; rr < 4; ++rr) {
      const float cr = __shfl(corr, 4 * g + rr);
      o[0][rr] *= cr; o[1][rr] *= cr; o[2][rr] *= cr; o[3][rr] *= cr;
    }

    bfx4 w0, w1;
    #pragma unroll
    for (int rr = 0; rr < 4; ++rr) { w0[rr] = (bh_t)pv0[rr]; w1[rr] = (bh_t)pv1[rr]; }
    *(bfx4*)&P[wave][r16][4 * g]      = w0;
    *(bfx4*)&P[wave][r16][16 + 4 * g] = w1;
    __builtin_amdgcn_wave_barrier();
    const bfx8 pf = *(const bfx8*)&P[wave][r16][8 * g];

    #pragma unroll
    for (int fi = 0; fi < 4; ++fi) {
      const bh_t* vp = vT + (size_t)(bh * HDIM + fi * 16 + r16) * TSEQ + kv0 + 8 * g;
      const bfx8 vf = *(const bfx8*)vp;
      o[fi] = mfma16(pf, vf, o[fi]);
    }
  }

  #pragma unroll
  for (int rr = 0; rr < 4; ++rr) {
    const float lr = __shfl(l, 4 * g + rr);
    const float inv = 1.0f / lr;
    const int trow = b * TSEQ + qbase + 4 * g + rr;
    #pragma unroll
    for (int fi = 0; fi < 4; ++fi)
      outb[(size_t)trow * CDIM + h * HDIM + fi * 16 + r16] = (bh_t)(o[fi][rr] * inv);
  }
}

// ---------------------------------------------------------------------------
// LayerNorm: f32 in -> bf16 out. One wave per row. (layer 0 entry only)
// ---------------------------------------------------------------------------
__global__ __launch_bounds__(256) void ln_fwd(
    const float* __restrict__ x, const float* __restrict__ w,
    const float* __restrict__ bb, bh_t* __restrict__ out)
{
  const int wave = threadIdx.x >> 6, lane = threadIdx.x & 63;
  const int row = blockIdx.x * 4 + wave;
  const float* xr = x + (size_t)row * CDIM;
  const int off = lane * 4;
  const float4 v0 = *(const float4*)(xr + off);
  const float4 v1 = *(const float4*)(xr + 256 + off);
  const float4 v2 = *(const float4*)(xr + 512 + off);
  float s  = v0.x + v0.y + v0.z + v0.w + v1.x + v1.y + v1.z + v1.w
           + v2.x + v2.y + v2.z + v2.w;
  float ss = v0.x*v0.x + v0.y*v0.y + v0.z*v0.z + v0.w*v0.w
           + v1.x*v1.x + v1.y*v1.y + v1.z*v1.z + v1.w*v1.w
           + v2.x*v2.x + v2.y*v2.y + v2.z*v2.z + v2.w*v2.w;
  #pragma unroll
  for (int d = 1; d < 64; d <<= 1) { s += __shfl_xor(s, d); ss += __shfl_xor(ss, d); }
  const float mean = s * (1.0f / 768.0f);
  const float inv = rsqrtf(ss * (1.0f / 768.0f) - mean * mean + 1e-5f);
  bh_t* orow = out + (size_t)row * CDIM;

  const float4 w0 = *(const float4*)(w + off),  b0 = *(const float4*)(bb + off);
  const float4 w1 = *(const float4*)(w + 256 + off), b1 = *(const float4*)(bb + 256 + off);
  const float4 w2 = *(const float4*)(w + 512 + off), b2 = *(const float4*)(bb + 512 + off);
  bfx4 o;
  o[0] = (bh_t)((v0.x - mean) * inv * w0.x + b0.x);
  o[1] = (bh_t)((v0.y - mean) * inv * w0.y + b0.y);
  o[2] = (bh_t)((v0.z - mean) * inv * w0.z + b0.z);
  o[3] = (bh_t)((v0.w - mean) * inv * w0.w + b0.w);
  *(bfx4*)(orow + off) = o;
  o[0] = (bh_t)((v1.x - mean) * inv * w1.x + b1.x);
  o[1] = (bh_t)((v1.y - mean) * inv * w1.y + b1.y);
  o[2] = (bh_t)((v1.z - mean) * inv * w1.z + b1.z);
  o[3] = (bh_t)((v1.w - mean) * inv * w1.w + b1.w);
  *(bfx4*)(orow + 256 + off) = o;
  o[0] = (bh_t)((v2.x - mean) * inv * w2.x + b2.x);
  o[1] = (bh_t)((v2.y - mean) * inv * w2.y + b2.y);
  o[2] = (bh_t)((v2.z - mean) * inv * w2.z + b2.z);
  o[3] = (bh_t)((v2.w - mean) * inv * w2.w + b2.w);
  *(bfx4*)(orow + 512 + off) = o;
}

// ---------------------------------------------------------------------------
__global__ void embed_k(const int* __restrict__ ids, const float* __restrict__ tok,
                        const float* __restrict__ pos, float* __restrict__ x)
{
  const int bt = blockIdx.x;
  const int t = bt & (TSEQ - 1);
  const int id = ids[bt];
  const float* tr = tok + (size_t)id * CDIM;
  const float* pr = pos + (size_t)t * CDIM;
  float* xr = x + (size_t)bt * CDIM;
  for (int j = threadIdx.x; j < CDIM; j += 256) xr[j] = tr[j] + pr[j];
}

// transpose + f32->bf16: in [L][R][Cn] -> out [L][Cn][R]
__global__ void tconv(const float* __restrict__ in, bh_t* __restrict__ out, int R, int Cn)
{
  __shared__ float tile[32][33];
  const size_t msz = (size_t)R * Cn;
  in  += msz * blockIdx.z;
  out += msz * blockIdx.z;
  const int tx = threadIdx.x & 31, ty = threadIdx.x >> 5;
  const int c0 = blockIdx.x * 32, r0 = blockIdx.y * 32;
  #pragma unroll
  for (int i = 0; i < 32; i += 8)
    tile[ty + i][tx] = in[(size_t)(r0 + ty + i) * Cn + c0 + tx];
  __syncthreads();
  #pragma unroll
  for (int i = 0; i < 32; i += 8)
    out[(size_t)(c0 + ty + i) * R + r0 + tx] = (bh_t)tile[tx][ty + i];
}

// tok_emb f32 [V][C] -> bf16 [VPAD][C], zero-padded rows
__global__ void embconv(const float* __restrict__ in, bh_t* __restrict__ out)
{
  const size_t i4 = ((size_t)blockIdx.x * 256 + threadIdx.x) * 4;
  if (i4 >= (size_t)VPAD * CDIM) return;
  const size_t vlim = (size_t)VOCAB * CDIM;
  float4 f = make_float4(0.f, 0.f, 0.f, 0.f);
  if (i4 < vlim) f = *(const float4*)(in + i4);
  bfx4 o;
  o[0] = (bh_t)f.x; o[1] = (bh_t)f.y; o[2] = (bh_t)f.z; o[3] = (bh_t)f.w;
  *(bfx4*)(out + i4) = o;
}

// V slice of qkv -> vT[bh*64 + d][t]
__global__ void vtrans(const bh_t* __restrict__ qkv, bh_t* __restrict__ vT)
{
  __shared__ bh_t tile[32][34];
  const int bh = blockIdx.z;
  const int b = bh / NHEAD, h = bh % NHEAD;
  const int d0 = blockIdx.x * 32, t0 = blockIdx.y * 32;
  const int tx = threadIdx.x & 31, ty = threadIdx.x >> 5;
  #pragma unroll
  for (int i = 0; i < 32; i += 8)
    tile[ty + i][tx] = qkv[(size_t)(b * TSEQ + t0 + ty + i) * (3 * CDIM) + 2 * CDIM + h * HDIM + d0 + tx];
  __syncthreads();
  #pragma unroll
  for (int i = 0; i < 32; i += 8)
    vT[(size_t)(bh * HDIM + d0 + ty + i) * TSEQ + t0 + tx] = tile[tx][ty + i];
}

// ---------------------------------------------------------------------------
extern "C" void kernel_launch(void* const* d_in, const int* in_sizes, int n_in,
                              void* d_out, int out_size, void* d_ws, size_t ws_size,
                              hipStream_t stream)
{
  (void)in_sizes; (void)n_in; (void)out_size; (void)ws_size;
  const int*   ids    = (const int*)d_in[0];
  const float* tok    = (const float*)d_in[1];
  const float* pos    = (const float*)d_in[2];
  const float* qkv_w  = (const float*)d_in[3];
  const float* qkv_b  = (const float*)d_in[4];
  const float* proj_w = (const float*)d_in[5];
  const float* proj_b = (const float*)d_in[6];
  const float* ln1_w  = (const float*)d_in[7];
  const float* ln1_b  = (const float*)d_in[8];
  const float* ln2_w  = (const float*)d_in[9];
  const float* ln2_b  = (const float*)d_in[10];
  const float* fc1_w  = (const float*)d_in[11];
  const float* fc1_b  = (const float*)d_in[12];
  const float* fc2_w  = (const float*)d_in[13];
  const float* fc2_b  = (const float*)d_in[14];
  const float* lnf_w  = (const float*)d_in[15];
  const float* lnf_b  = (const float*)d_in[16];

  // ---- scratch in ws (activations + embT), ~153 MB
  char* wp = (char*)d_ws;
  auto carve = [&](size_t bytes) { char* p = wp; wp += (bytes + 255) & ~(size_t)255; return p; };
  float* x     = (float*)carve((size_t)MROWS * CDIM * 4);
  bh_t*  hbuf  = (bh_t*)carve((size_t)MROWS * CDIM * 2);
  bh_t*  qkvb  = (bh_t*)carve((size_t)MROWS * 3 * CDIM * 2);
  bh_t*  vT    = (bh_t*)carve((size_t)48 * HDIM * TSEQ * 2);
  bh_t*  attno = (bh_t*)carve((size_t)MROWS * CDIM * 2);
  bh_t*  mlp1  = (bh_t*)carve((size_t)MROWS * 3072 * 2);
  bh_t*  embT  = (bh_t*)carve((size_t)VPAD * CDIM * 2);

  // ---- staged in d_out (dead before lm_head overwrites it), ~270 MB of 823
  char* op = (char*)d_out;
  auto carveO = [&](size_t bytes) { char* p = op; op += (bytes + 255) & ~(size_t)255; return p; };
  bh_t* qkvwT  = (bh_t*)carveO((size_t)NLAYER * 3 * CDIM * CDIM * 2);
  bh_t* projwT = (bh_t*)carveO((size_t)NLAYER * CDIM * CDIM * 2);
  bh_t* fc1wT  = (bh_t*)carveO((size_t)NLAYER * 3072 * CDIM * 2);
  bh_t* fc2wT  = (bh_t*)carveO((size_t)NLAYER * CDIM * 3072 * 2);
  float* skpart = (float*)carveO((size_t)4 * MROWS * CDIM * 4);   // split-K partials

  tconv<<<dim3(2304 / 32, 768 / 32, NLAYER), 256, 0, stream>>>(qkv_w, qkvwT, 768, 2304);
  tconv<<<dim3(768 / 32, 768 / 32, NLAYER), 256, 0, stream>>>(proj_w, projwT, 768, 768);
  tconv<<<dim3(3072 / 32, 768 / 32, NLAYER), 256, 0, stream>>>(fc1_w, fc1wT, 768, 3072);
  tconv<<<dim3(768 / 32, 3072 / 32, NLAYER), 256, 0, stream>>>(fc2_w, fc2wT, 3072, 768);
  embconv<<<((VPAD * CDIM / 4) + 255) / 256, 256, 0, stream>>>(tok, embT);
  embed_k<<<MROWS, 256, 0, stream>>>(ids, tok, pos, x);

  ln_fwd<<<MROWS / 4, 256, 0, stream>>>(x, ln1_w, ln1_b, hbuf);
  for (int l = 0; l < NLAYER; ++l) {
    // qkv: grid 16x18 = 288 blocks
    gemm256n<<<dim3(16, 18), 512, 0, stream>>>(hbuf, qkvwT + (size_t)l * 3 * CDIM * CDIM,
        qkv_b + l * 3 * CDIM, qkvb, MROWS, 3 * CDIM, CDIM, CDIM, 1 | 8);
    vtrans<<<dim3(2, 32, 48), 256, 0, stream>>>(qkvb, vT);
    attn_fwd<<<768, 256, 0, stream>>>(qkvb, vT, attno);
    // proj: split-K x4 (K_eff=192, nt=6), grid 16x6x4 = 384 blocks
    gemm256n<<<dim3(16, 6, 4), 512, 0, stream>>>(attno,
        projwT + (size_t)l * CDIM * CDIM, nullptr, skpart, MROWS, CDIM, 192, CDIM, 0);
    skred_ln<<<MROWS / 4, 256, 0, stream>>>(skpart, proj_b + l * CDIM, x,
        ln2_w + l * CDIM, ln2_b + l * CDIM, hbuf, 4);
    // fc1: grid 16x24 = 384 blocks
    gemm256n<<<dim3(16, 24), 512, 0, stream>>>(hbuf, fc1wT + (size_t)l * 3072 * CDIM,
        fc1_b + l * 3072, mlp1, MROWS, 3072, CDIM, CDIM, 1 | 4 | 8);
    // fc2: split-K x4 (K_eff=768, nt=24), grid 16x6x4 = 384 blocks
    gemm256n<<<dim3(16, 6, 4), 512, 0, stream>>>(mlp1, fc2wT + (size_t)l * CDIM * 3072,
        nullptr, skpart, MROWS, CDIM, 768, 3072, 0);
    const float* nw = (l + 1 < NLAYER) ? ln1_w + (l + 1) * CDIM : lnf_w;
    const float* nb = (l + 1 < NLAYER) ? ln1_b + (l + 1) * CDIM : lnf_b;
    skred_ln<<<MROWS / 4, 256, 0, stream>>>(skpart, fc2_b + l * CDIM, x, nw, nb, hbuf, 4);
  }
  // lm_head: grid 16x393 = 6288 blocks (50304 = 393*128 covers VOCAB)
  gemm256n<<<dim3(16, 393), 512, 0, stream>>>(hbuf, embT, nullptr,
      (float*)d_out, MROWS, VOCAB, CDIM, CDIM, 0);
}